// Round 1
// baseline (2455.381 us; speedup 1.0000x reference)
//
#include <hip/hip_runtime.h>
#include <cstdint>
#include <cstddef>

// ---------------------------------------------------------------------------
// gemm_nt: C[i,j] = sum_k A[i,k] * W[j,k] + bias[j]
// A: (I,K) row-major; W: (J,K) row-major; C: (I, ldc) row-major.
// Grid: (J/64, I/64). Block: 256. Tile 64x64x16, 4x4 per thread.
// ---------------------------------------------------------------------------
__global__ __launch_bounds__(256) void gemm_nt(
    const float* __restrict__ A, const float* __restrict__ W,
    const float* __restrict__ bias, float* __restrict__ C,
    int K, int ldc)
{
    __shared__ float As[64][17];
    __shared__ float Ws[64][17];
    const int j0 = blockIdx.x * 64;
    const int i0 = blockIdx.y * 64;
    const int tid = threadIdx.x;
    const int tx = tid & 15, ty = tid >> 4;
    const int lr = tid >> 4, lc = tid & 15;
    float acc[4][4] = {};

    for (int k0 = 0; k0 < K; k0 += 16) {
#pragma unroll
        for (int rr = 0; rr < 4; ++rr) {
            int r = lr + rr * 16;
            As[r][lc] = A[(size_t)(i0 + r) * K + k0 + lc];
            Ws[r][lc] = W[(size_t)(j0 + r) * K + k0 + lc];
        }
        __syncthreads();
#pragma unroll
        for (int kk = 0; kk < 16; ++kk) {
            float av[4], wv[4];
#pragma unroll
            for (int r = 0; r < 4; ++r) av[r] = As[ty * 4 + r][kk];
#pragma unroll
            for (int c = 0; c < 4; ++c) wv[c] = Ws[tx * 4 + c][kk];
#pragma unroll
            for (int r = 0; r < 4; ++r)
#pragma unroll
                for (int c = 0; c < 4; ++c)
                    acc[r][c] = fmaf(av[r], wv[c], acc[r][c]);
        }
        __syncthreads();
    }
#pragma unroll
    for (int r = 0; r < 4; ++r) {
        int i = i0 + ty * 4 + r;
#pragma unroll
        for (int c = 0; c < 4; ++c) {
            int j = j0 + tx * 4 + c;
            C[(size_t)i * ldc + j] = acc[r][c] + bias[j];
        }
    }
}

// ---------------------------------------------------------------------------
// gemm_nn_lift: C[i,j] = sum_k A[i,k] * W[z][k,j] + bias[z][j]
// A: (64,K); W: (Z,K,J) row-major; bias: (Z,J); C slot offset z*J within row.
// Grid: (J/64, 1, Z). Block 256.
// ---------------------------------------------------------------------------
__global__ __launch_bounds__(256) void gemm_nn_lift(
    const float* __restrict__ A, const float* __restrict__ W,
    const float* __restrict__ bias, float* __restrict__ C,
    int K, int J, int ldc)
{
    const int z = blockIdx.z;
    W += (size_t)z * K * J;
    bias += (size_t)z * J;
    C += (size_t)z * J;

    __shared__ float As[64][17];
    __shared__ float Ws[16][65];
    const int j0 = blockIdx.x * 64;
    const int tid = threadIdx.x;
    const int tx = tid & 15, ty = tid >> 4;
    float acc[4][4] = {};

    for (int k0 = 0; k0 < K; k0 += 16) {
        {
            int r = tid >> 4, c = tid & 15;
#pragma unroll
            for (int rr = 0; rr < 4; ++rr)
                As[r + rr * 16][c] = A[(size_t)(r + rr * 16) * K + k0 + c];
            int kk = tid >> 6;   // 0..3
            int jj = tid & 63;
#pragma unroll
            for (int kx = 0; kx < 4; ++kx)
                Ws[kk + kx * 4][jj] = W[(size_t)(k0 + kk + kx * 4) * J + j0 + jj];
        }
        __syncthreads();
#pragma unroll
        for (int kk = 0; kk < 16; ++kk) {
            float av[4], wv[4];
#pragma unroll
            for (int r = 0; r < 4; ++r) av[r] = As[ty * 4 + r][kk];
#pragma unroll
            for (int c = 0; c < 4; ++c) wv[c] = Ws[kk][tx * 4 + c];
#pragma unroll
            for (int r = 0; r < 4; ++r)
#pragma unroll
                for (int c = 0; c < 4; ++c)
                    acc[r][c] = fmaf(av[r], wv[c], acc[r][c]);
        }
        __syncthreads();
    }
#pragma unroll
    for (int r = 0; r < 4; ++r) {
        int i = ty * 4 + r;
#pragma unroll
        for (int c = 0; c < 4; ++c) {
            int j = j0 + tx * 4 + c;
            C[(size_t)i * ldc + j] = acc[r][c] + bias[j];
        }
    }
}

// ---------------------------------------------------------------------------
// attn1: single-query-token MHA core for one (b,h).
// qp: (B, nh*64); kv: (M, 2*d) rows = [k(d) | v(d)]; out: (B, d).
// Grid: (nh, B). Block 256. M=2048 scores live in LDS.
// ---------------------------------------------------------------------------
__global__ __launch_bounds__(256) void attn1(
    const float* __restrict__ qp, const float* __restrict__ kv,
    const uint8_t* __restrict__ mask, float* __restrict__ out,
    int nh, int d)
{
    const int h = blockIdx.x, b = blockIdx.y;
    const int tid = threadIdx.x;
    __shared__ __align__(16) float sc[2048];
    __shared__ __align__(16) float qs[64];
    __shared__ float red[4];
    __shared__ float s_max, s_inv;

    if (tid < 64) qs[tid] = qp[(size_t)b * d + h * 64 + tid];
    __syncthreads();

    const int twoD = 2 * d;
    float lmax = -1e30f;
    for (int m = tid; m < 2048; m += 256) {
        const float4* kr = (const float4*)(kv + (size_t)m * twoD + h * 64);
        const float4* q4 = (const float4*)qs;
        float s = 0.f;
#pragma unroll
        for (int j = 0; j < 16; ++j) {
            float4 kk = kr[j], qq = q4[j];
            s += kk.x * qq.x + kk.y * qq.y + kk.z * qq.z + kk.w * qq.w;
        }
        s *= 0.125f;  // 1/sqrt(64)
        if (mask[(size_t)b * 2048 + m]) s = -1e9f;
        sc[m] = s;
        lmax = fmaxf(lmax, s);
    }
#pragma unroll
    for (int off = 32; off; off >>= 1) lmax = fmaxf(lmax, __shfl_down(lmax, off));
    if ((tid & 63) == 0) red[tid >> 6] = lmax;
    __syncthreads();
    if (tid == 0) s_max = fmaxf(fmaxf(red[0], red[1]), fmaxf(red[2], red[3]));
    __syncthreads();
    const float mx = s_max;

    float lsum = 0.f;
    for (int m = tid; m < 2048; m += 256) {
        float e = expf(sc[m] - mx);
        sc[m] = e;
        lsum += e;
    }
#pragma unroll
    for (int off = 32; off; off >>= 1) lsum += __shfl_down(lsum, off);
    if ((tid & 63) == 0) red[tid >> 6] = lsum;
    __syncthreads();
    if (tid == 0) s_inv = 1.f / (red[0] + red[1] + red[2] + red[3]);
    __syncthreads();
    const float inv = s_inv;

    const int lane = tid & 63, grp = tid >> 6;
    float acc = 0.f;
    for (int m = grp; m < 2048; m += 4)
        acc += sc[m] * kv[(size_t)m * twoD + d + h * 64 + lane];
    __syncthreads();            // all sc reads done
    sc[grp * 64 + lane] = acc;  // reuse sc for partials
    __syncthreads();
    if (grp == 0) {
        float o = (sc[lane] + sc[64 + lane] + sc[128 + lane] + sc[192 + lane]) * inv;
        out[(size_t)b * d + h * 64 + lane] = o;
    }
}

// ---------------------------------------------------------------------------
// ln_kernel: in-place LayerNorm over last dim (4096) of (1024, 4096).
// ---------------------------------------------------------------------------
__global__ __launch_bounds__(256) void ln_kernel(
    float* __restrict__ x, const float* __restrict__ g, const float* __restrict__ bb)
{
    const int row = blockIdx.x;
    float* xr = x + (size_t)row * 4096;
    const int tid = threadIdx.x;
    float v[16];
    float sum = 0.f, sumsq = 0.f;
#pragma unroll
    for (int i = 0; i < 16; ++i) {
        v[i] = xr[tid + i * 256];
        sum += v[i];
        sumsq += v[i] * v[i];
    }
    __shared__ float rs[4], rq[4];
#pragma unroll
    for (int off = 32; off; off >>= 1) {
        sum += __shfl_down(sum, off);
        sumsq += __shfl_down(sumsq, off);
    }
    if ((tid & 63) == 0) { rs[tid >> 6] = sum; rq[tid >> 6] = sumsq; }
    __syncthreads();
    const float ts = rs[0] + rs[1] + rs[2] + rs[3];
    const float tq = rq[0] + rq[1] + rq[2] + rq[3];
    const float mu = ts * (1.f / 4096.f);
    const float var = tq * (1.f / 4096.f) - mu * mu;
    const float r = rsqrtf(var + 1e-5f);
#pragma unroll
    for (int i = 0; i < 16; ++i) {
        int e = tid + i * 256;
        xr[e] = (v[i] - mu) * r * g[e] + bb[e];
    }
}

// ---------------------------------------------------------------------------
extern "C" void kernel_launch(void* const* d_in, const int* in_sizes, int n_in,
                              void* d_out, int out_size, void* d_ws, size_t ws_size,
                              hipStream_t stream)
{
    const float*   hs     = (const float*)d_in[0];
    const float*   fib_t  = (const float*)d_in[1];
    const float*   fib_p  = (const float*)d_in[2];
    const float*   fib_c  = (const float*)d_in[3];
    const uint8_t* mask   = (const uint8_t*)d_in[4];
    const float* Wq_t   = (const float*)d_in[5];  const float* bq_t   = (const float*)d_in[6];
    const float* Wq_p   = (const float*)d_in[7];  const float* bq_p   = (const float*)d_in[8];
    const float* Wq_c   = (const float*)d_in[9];  const float* bq_c   = (const float*)d_in[10];
    const float* Wqkv_t = (const float*)d_in[11]; const float* bqkv_t = (const float*)d_in[12];
    const float* Wo_t   = (const float*)d_in[13]; const float* bo_t   = (const float*)d_in[14];
    const float* Wqkv_p = (const float*)d_in[15]; const float* bqkv_p = (const float*)d_in[16];
    const float* Wo_p   = (const float*)d_in[17]; const float* bo_p   = (const float*)d_in[18];
    const float* Wqkv_c = (const float*)d_in[19]; const float* bqkv_c = (const float*)d_in[20];
    const float* Wo_c   = (const float*)d_in[21]; const float* bo_c   = (const float*)d_in[22];
    const float* Wl_t   = (const float*)d_in[23]; const float* bl_t   = (const float*)d_in[24];
    const float* Wl_p   = (const float*)d_in[25]; const float* bl_p   = (const float*)d_in[26];
    const float* Wl_c   = (const float*)d_in[27]; const float* bl_c   = (const float*)d_in[28];
    const float* ln_g   = (const float*)d_in[29]; const float* ln_b   = (const float*)d_in[30];

    float* ws = (float*)d_ws;
    float* q_t  = ws; ws += 64 * 256;
    float* q_p  = ws; ws += 64 * 512;
    float* q_c  = ws; ws += 64 * 1024;
    float* qp_t = ws; ws += 64 * 256;
    float* qp_p = ws; ws += 64 * 512;
    float* qp_c = ws; ws += 64 * 1024;
    float* kv_t = ws; ws += 2048 * 512;
    float* kv_p = ws; ws += 2048 * 1024;
    float* kv_c = ws; ws += 2048 * 2048;
    float* o_t  = ws; ws += 64 * 256;
    float* o_p  = ws; ws += 64 * 512;
    float* o_c  = ws; ws += 64 * 1024;
    float* po_t = ws; ws += 64 * 256;
    float* po_p = ws; ws += 64 * 512;
    float* po_c = ws; ws += 64 * 1024;
    float* out  = (float*)d_out;

    const dim3 blk(256);

    // bundle query heads: q_f = hs @ Wq_f^T + bq_f   (64 x d_f, K=4096)
    gemm_nt<<<dim3(4, 1),  blk, 0, stream>>>(hs, Wq_t, bq_t, q_t, 4096, 256);
    gemm_nt<<<dim3(8, 1),  blk, 0, stream>>>(hs, Wq_p, bq_p, q_p, 4096, 512);
    gemm_nt<<<dim3(16, 1), blk, 0, stream>>>(hs, Wq_c, bq_c, q_c, 4096, 1024);

    // q in-proj: qp = q @ Wq_in^T + bq_in  (rows 0..d of Wqkv)
    gemm_nt<<<dim3(4, 1),  blk, 0, stream>>>(q_t, Wqkv_t, bqkv_t, qp_t, 256, 256);
    gemm_nt<<<dim3(8, 1),  blk, 0, stream>>>(q_p, Wqkv_p, bqkv_p, qp_p, 512, 512);
    gemm_nt<<<dim3(16, 1), blk, 0, stream>>>(q_c, Wqkv_c, bqkv_c, qp_c, 1024, 1024);

    // k/v proj combined: kv = fiber @ Wkv^T + bkv  (J = 2d, rows d..3d of Wqkv)
    gemm_nt<<<dim3(8, 32),  blk, 0, stream>>>(fib_t, Wqkv_t + 256 * 256,   bqkv_t + 256,  kv_t, 256, 512);
    gemm_nt<<<dim3(16, 32), blk, 0, stream>>>(fib_p, Wqkv_p + 512 * 512,   bqkv_p + 512,  kv_p, 512, 1024);
    gemm_nt<<<dim3(32, 32), blk, 0, stream>>>(fib_c, Wqkv_c + 1024 * 1024, bqkv_c + 1024, kv_c, 1024, 2048);

    // attention
    attn1<<<dim3(4, 64),  blk, 0, stream>>>(qp_t, kv_t, mask, o_t, 4, 256);
    attn1<<<dim3(8, 64),  blk, 0, stream>>>(qp_p, kv_p, mask, o_p, 8, 512);
    attn1<<<dim3(16, 64), blk, 0, stream>>>(qp_c, kv_c, mask, o_c, 16, 1024);

    // out proj
    gemm_nt<<<dim3(4, 1),  blk, 0, stream>>>(o_t, Wo_t, bo_t, po_t, 256, 256);
    gemm_nt<<<dim3(8, 1),  blk, 0, stream>>>(o_p, Wo_p, bo_p, po_p, 512, 512);
    gemm_nt<<<dim3(16, 1), blk, 0, stream>>>(o_c, Wo_c, bo_c, po_c, 1024, 1024);

    // lifts -> prefix (B, 16, 4096) written straight into d_out
    gemm_nn_lift<<<dim3(64, 1, 4), blk, 0, stream>>>(po_t, Wl_t, bl_t, out + 0 * 4096,  256,  4096, 16 * 4096);
    gemm_nn_lift<<<dim3(64, 1, 8), blk, 0, stream>>>(po_p, Wl_p, bl_p, out + 4 * 4096,  512,  4096, 16 * 4096);
    gemm_nn_lift<<<dim3(64, 1, 4), blk, 0, stream>>>(po_c, Wl_c, bl_c, out + 12 * 4096, 1024, 4096, 16 * 4096);

    // layernorm in place on d_out
    ln_kernel<<<dim3(1024), blk, 0, stream>>>(out, ln_g, ln_b);
}

// Round 2
// 1427.012 us; speedup vs baseline: 1.7206x; 1.7206x over previous
//
#include <hip/hip_runtime.h>
#include <cstdint>
#include <cstddef>

// ---------------------------------------------------------------------------
// gemm_nt_sk: C[i,j] (+)= sum_{k in split} A[i,k] * W[j,k]  (+ bias[j] on kz==0)
// A: (I,K) row-major; W: (J,K) row-major; C: (I, ldc) row-major.
// Grid: (J/64, I/64, S). Block: 256. Tile 64x64x16, 4x4 per thread.
// If S>1, C must be pre-zeroed (atomicAdd accumulation).
// ---------------------------------------------------------------------------
__global__ __launch_bounds__(256) void gemm_nt_sk(
    const float* __restrict__ A, const float* __restrict__ W,
    const float* __restrict__ bias, float* __restrict__ C,
    int K, int ldc, int Kc)
{
    __shared__ float As[64][17];
    __shared__ float Ws[64][17];
    const int j0 = blockIdx.x * 64;
    const int i0 = blockIdx.y * 64;
    const int kz = blockIdx.z;
    const int kbeg = kz * Kc;
    const int kend = kbeg + Kc;
    const int tid = threadIdx.x;
    const int tx = tid & 15, ty = tid >> 4;
    const int lr = tid >> 4, lc = tid & 15;
    float acc[4][4] = {};

    for (int k0 = kbeg; k0 < kend; k0 += 16) {
#pragma unroll
        for (int rr = 0; rr < 4; ++rr) {
            int r = lr + rr * 16;
            As[r][lc] = A[(size_t)(i0 + r) * K + k0 + lc];
            Ws[r][lc] = W[(size_t)(j0 + r) * K + k0 + lc];
        }
        __syncthreads();
#pragma unroll
        for (int kk = 0; kk < 16; ++kk) {
            float av[4], wv[4];
#pragma unroll
            for (int r = 0; r < 4; ++r) av[r] = As[ty * 4 + r][kk];
#pragma unroll
            for (int c = 0; c < 4; ++c) wv[c] = Ws[tx * 4 + c][kk];
#pragma unroll
            for (int r = 0; r < 4; ++r)
#pragma unroll
                for (int c = 0; c < 4; ++c)
                    acc[r][c] = fmaf(av[r], wv[c], acc[r][c]);
        }
        __syncthreads();
    }
    const bool single = (gridDim.z == 1);
#pragma unroll
    for (int r = 0; r < 4; ++r) {
        int i = i0 + ty * 4 + r;
#pragma unroll
        for (int c = 0; c < 4; ++c) {
            int j = j0 + tx * 4 + c;
            float v = acc[r][c] + ((kz == 0) ? bias[j] : 0.f);
            if (single) C[(size_t)i * ldc + j] = v;
            else        atomicAdd(&C[(size_t)i * ldc + j], v);
        }
    }
}

// ---------------------------------------------------------------------------
// gemm_nn_lift: C[i,j] (+)= sum_{k in split} A[i,k]*W[z][k,j] (+ bias[z][j])
// A: (64,K); W: (Z,K,J) row-major; bias: (Z,J); C slot offset z*J within row.
// Grid: (J/64, S, Z). Block 256. C pre-zeroed; atomicAdd accumulation.
// ---------------------------------------------------------------------------
__global__ __launch_bounds__(256) void gemm_nn_lift(
    const float* __restrict__ A, const float* __restrict__ W,
    const float* __restrict__ bias, float* __restrict__ C,
    int K, int J, int ldc, int Kc)
{
    const int z = blockIdx.z;
    W += (size_t)z * K * J;
    bias += (size_t)z * J;
    C += (size_t)z * J;

    __shared__ float As[64][17];
    __shared__ float Ws[16][65];
    const int j0 = blockIdx.x * 64;
    const int kz = blockIdx.y;
    const int kbeg = kz * Kc;
    const int kend = kbeg + Kc;
    const int tid = threadIdx.x;
    const int tx = tid & 15, ty = tid >> 4;
    float acc[4][4] = {};

    for (int k0 = kbeg; k0 < kend; k0 += 16) {
        {
            int r = tid >> 4, c = tid & 15;
#pragma unroll
            for (int rr = 0; rr < 4; ++rr)
                As[r + rr * 16][c] = A[(size_t)(r + rr * 16) * K + k0 + c];
            int kk = tid >> 6;   // 0..3
            int jj = tid & 63;
#pragma unroll
            for (int kx = 0; kx < 4; ++kx)
                Ws[kk + kx * 4][jj] = W[(size_t)(k0 + kk + kx * 4) * J + j0 + jj];
        }
        __syncthreads();
#pragma unroll
        for (int kk = 0; kk < 16; ++kk) {
            float av[4], wv[4];
#pragma unroll
            for (int r = 0; r < 4; ++r) av[r] = As[ty * 4 + r][kk];
#pragma unroll
            for (int c = 0; c < 4; ++c) wv[c] = Ws[kk][tx * 4 + c];
#pragma unroll
            for (int r = 0; r < 4; ++r)
#pragma unroll
                for (int c = 0; c < 4; ++c)
                    acc[r][c] = fmaf(av[r], wv[c], acc[r][c]);
        }
        __syncthreads();
    }
#pragma unroll
    for (int r = 0; r < 4; ++r) {
        int i = ty * 4 + r;
#pragma unroll
        for (int c = 0; c < 4; ++c) {
            int j = j0 + tx * 4 + c;
            float v = acc[r][c] + ((kz == 0) ? bias[j] : 0.f);
            atomicAdd(&C[(size_t)i * ldc + j], v);
        }
    }
}

// ---------------------------------------------------------------------------
// attn1: single-query-token MHA core for one (b,h).
// qp: (B, nh*64); kv: (M, 2*d) rows = [k(d) | v(d)]; out: (B, d).
// Grid: (nh, B). Block 256. M=2048 scores live in LDS.
// ---------------------------------------------------------------------------
__global__ __launch_bounds__(256) void attn1(
    const float* __restrict__ qp, const float* __restrict__ kv,
    const uint8_t* __restrict__ mask, float* __restrict__ out,
    int nh, int d)
{
    const int h = blockIdx.x, b = blockIdx.y;
    const int tid = threadIdx.x;
    __shared__ __align__(16) float sc[2048];
    __shared__ __align__(16) float qs[64];
    __shared__ float red[4];
    __shared__ float s_max, s_inv;

    if (tid < 64) qs[tid] = qp[(size_t)b * d + h * 64 + tid];
    __syncthreads();

    const int twoD = 2 * d;
    float lmax = -1e30f;
    for (int m = tid; m < 2048; m += 256) {
        const float4* kr = (const float4*)(kv + (size_t)m * twoD + h * 64);
        const float4* q4 = (const float4*)qs;
        float s = 0.f;
#pragma unroll
        for (int j = 0; j < 16; ++j) {
            float4 kk = kr[j], qq = q4[j];
            s += kk.x * qq.x + kk.y * qq.y + kk.z * qq.z + kk.w * qq.w;
        }
        s *= 0.125f;  // 1/sqrt(64)
        if (mask[(size_t)b * 2048 + m]) s = -1e9f;
        sc[m] = s;
        lmax = fmaxf(lmax, s);
    }
#pragma unroll
    for (int off = 32; off; off >>= 1) lmax = fmaxf(lmax, __shfl_down(lmax, off));
    if ((tid & 63) == 0) red[tid >> 6] = lmax;
    __syncthreads();
    if (tid == 0) s_max = fmaxf(fmaxf(red[0], red[1]), fmaxf(red[2], red[3]));
    __syncthreads();
    const float mx = s_max;

    float lsum = 0.f;
    for (int m = tid; m < 2048; m += 256) {
        float e = expf(sc[m] - mx);
        sc[m] = e;
        lsum += e;
    }
#pragma unroll
    for (int off = 32; off; off >>= 1) lsum += __shfl_down(lsum, off);
    if ((tid & 63) == 0) red[tid >> 6] = lsum;
    __syncthreads();
    if (tid == 0) s_inv = 1.f / (red[0] + red[1] + red[2] + red[3]);
    __syncthreads();
    const float inv = s_inv;

    const int lane = tid & 63, grp = tid >> 6;
    float acc = 0.f;
    for (int m = grp; m < 2048; m += 4)
        acc += sc[m] * kv[(size_t)m * twoD + d + h * 64 + lane];
    __syncthreads();            // all sc reads done
    sc[grp * 64 + lane] = acc;  // reuse sc for partials
    __syncthreads();
    if (grp == 0) {
        float o = (sc[lane] + sc[64 + lane] + sc[128 + lane] + sc[192 + lane]) * inv;
        out[(size_t)b * d + h * 64 + lane] = o;
    }
}

// ---------------------------------------------------------------------------
// ln_kernel: in-place LayerNorm over last dim (4096) of (1024, 4096).
// ---------------------------------------------------------------------------
__global__ __launch_bounds__(256) void ln_kernel(
    float* __restrict__ x, const float* __restrict__ g, const float* __restrict__ bb)
{
    const int row = blockIdx.x;
    float* xr = x + (size_t)row * 4096;
    const int tid = threadIdx.x;
    float v[16];
    float sum = 0.f, sumsq = 0.f;
#pragma unroll
    for (int i = 0; i < 16; ++i) {
        v[i] = xr[tid + i * 256];
        sum += v[i];
        sumsq += v[i] * v[i];
    }
    __shared__ float rs[4], rq[4];
#pragma unroll
    for (int off = 32; off; off >>= 1) {
        sum += __shfl_down(sum, off);
        sumsq += __shfl_down(sumsq, off);
    }
    if ((tid & 63) == 0) { rs[tid >> 6] = sum; rq[tid >> 6] = sumsq; }
    __syncthreads();
    const float ts = rs[0] + rs[1] + rs[2] + rs[3];
    const float tq = rq[0] + rq[1] + rq[2] + rq[3];
    const float mu = ts * (1.f / 4096.f);
    const float var = tq * (1.f / 4096.f) - mu * mu;
    const float r = rsqrtf(var + 1e-5f);
#pragma unroll
    for (int i = 0; i < 16; ++i) {
        int e = tid + i * 256;
        xr[e] = (v[i] - mu) * r * g[e] + bb[e];
    }
}

// ---------------------------------------------------------------------------
extern "C" void kernel_launch(void* const* d_in, const int* in_sizes, int n_in,
                              void* d_out, int out_size, void* d_ws, size_t ws_size,
                              hipStream_t stream)
{
    const float*   hs     = (const float*)d_in[0];
    const float*   fib_t  = (const float*)d_in[1];
    const float*   fib_p  = (const float*)d_in[2];
    const float*   fib_c  = (const float*)d_in[3];
    const uint8_t* mask   = (const uint8_t*)d_in[4];
    const float* Wq_t   = (const float*)d_in[5];  const float* bq_t   = (const float*)d_in[6];
    const float* Wq_p   = (const float*)d_in[7];  const float* bq_p   = (const float*)d_in[8];
    const float* Wq_c   = (const float*)d_in[9];  const float* bq_c   = (const float*)d_in[10];
    const float* Wqkv_t = (const float*)d_in[11]; const float* bqkv_t = (const float*)d_in[12];
    const float* Wo_t   = (const float*)d_in[13]; const float* bo_t   = (const float*)d_in[14];
    const float* Wqkv_p = (const float*)d_in[15]; const float* bqkv_p = (const float*)d_in[16];
    const float* Wo_p   = (const float*)d_in[17]; const float* bo_p   = (const float*)d_in[18];
    const float* Wqkv_c = (const float*)d_in[19]; const float* bqkv_c = (const float*)d_in[20];
    const float* Wo_c   = (const float*)d_in[21]; const float* bo_c   = (const float*)d_in[22];
    const float* Wl_t   = (const float*)d_in[23]; const float* bl_t   = (const float*)d_in[24];
    const float* Wl_p   = (const float*)d_in[25]; const float* bl_p   = (const float*)d_in[26];
    const float* Wl_c   = (const float*)d_in[27]; const float* bl_c   = (const float*)d_in[28];
    const float* ln_g   = (const float*)d_in[29]; const float* ln_b   = (const float*)d_in[30];

    // workspace layout: zero-needed regions first (q, qp, po), then o, then kv
    float* ws = (float*)d_ws;
    float* zbase = ws;
    float* q_t  = ws; ws += 64 * 256;
    float* q_p  = ws; ws += 64 * 512;
    float* q_c  = ws; ws += 64 * 1024;
    float* qp_t = ws; ws += 64 * 256;
    float* qp_p = ws; ws += 64 * 512;
    float* qp_c = ws; ws += 64 * 1024;
    float* po_t = ws; ws += 64 * 256;
    float* po_p = ws; ws += 64 * 512;
    float* po_c = ws; ws += 64 * 1024;
    size_t zcount = (size_t)(ws - zbase);          // 344064 floats
    float* o_t  = ws; ws += 64 * 256;
    float* o_p  = ws; ws += 64 * 512;
    float* o_c  = ws; ws += 64 * 1024;
    float* kv_t = ws; ws += 2048 * 512;
    float* kv_p = ws; ws += 2048 * 1024;
    float* kv_c = ws; ws += 2048 * 2048;
    float* out  = (float*)d_out;

    const dim3 blk(256);

    // zero atomic-accumulation targets
    hipMemsetAsync(zbase, 0, zcount * sizeof(float), stream);
    hipMemsetAsync(out, 0, (size_t)out_size * sizeof(float), stream);

    // bundle query heads: q_f = hs @ Wq_f^T + bq_f   (64 x d_f, K=4096, S=16)
    gemm_nt_sk<<<dim3(4, 1, 16),  blk, 0, stream>>>(hs, Wq_t, bq_t, q_t, 4096, 256, 256);
    gemm_nt_sk<<<dim3(8, 1, 16),  blk, 0, stream>>>(hs, Wq_p, bq_p, q_p, 4096, 512, 256);
    gemm_nt_sk<<<dim3(16, 1, 16), blk, 0, stream>>>(hs, Wq_c, bq_c, q_c, 4096, 1024, 256);

    // k/v proj combined: kv = fiber @ Wkv^T + bkv  (J = 2d, rows d..3d of Wqkv)
    gemm_nt_sk<<<dim3(8, 32, 1),  blk, 0, stream>>>(fib_t, Wqkv_t + 256 * 256,   bqkv_t + 256,  kv_t, 256, 512, 256);
    gemm_nt_sk<<<dim3(16, 32, 1), blk, 0, stream>>>(fib_p, Wqkv_p + 512 * 512,   bqkv_p + 512,  kv_p, 512, 1024, 512);
    gemm_nt_sk<<<dim3(32, 32, 1), blk, 0, stream>>>(fib_c, Wqkv_c + 1024 * 1024, bqkv_c + 1024, kv_c, 1024, 2048, 1024);

    // q in-proj: qp = q @ Wq_in^T + bq_in  (rows 0..d of Wqkv)
    gemm_nt_sk<<<dim3(4, 1, 4),  blk, 0, stream>>>(q_t, Wqkv_t, bqkv_t, qp_t, 256, 256, 64);
    gemm_nt_sk<<<dim3(8, 1, 8),  blk, 0, stream>>>(q_p, Wqkv_p, bqkv_p, qp_p, 512, 512, 64);
    gemm_nt_sk<<<dim3(16, 1, 8), blk, 0, stream>>>(q_c, Wqkv_c, bqkv_c, qp_c, 1024, 1024, 128);

    // attention
    attn1<<<dim3(4, 64),  blk, 0, stream>>>(qp_t, kv_t, mask, o_t, 4, 256);
    attn1<<<dim3(8, 64),  blk, 0, stream>>>(qp_p, kv_p, mask, o_p, 8, 512);
    attn1<<<dim3(16, 64), blk, 0, stream>>>(qp_c, kv_c, mask, o_c, 16, 1024);

    // out proj (split-K, atomic into zeroed po_*)
    gemm_nt_sk<<<dim3(4, 1, 4),  blk, 0, stream>>>(o_t, Wo_t, bo_t, po_t, 256, 256, 64);
    gemm_nt_sk<<<dim3(8, 1, 8),  blk, 0, stream>>>(o_p, Wo_p, bo_p, po_p, 512, 512, 64);
    gemm_nt_sk<<<dim3(16, 1, 8), blk, 0, stream>>>(o_c, Wo_c, bo_c, po_c, 1024, 1024, 128);

    // lifts -> prefix (B, 16, 4096) atomic-accumulated into zeroed d_out
    gemm_nn_lift<<<dim3(64, 2, 4), blk, 0, stream>>>(po_t, Wl_t, bl_t, out + 0 * 4096,  256,  4096, 16 * 4096, 128);
    gemm_nn_lift<<<dim3(64, 2, 8), blk, 0, stream>>>(po_p, Wl_p, bl_p, out + 4 * 4096,  512,  4096, 16 * 4096, 256);
    gemm_nn_lift<<<dim3(64, 4, 4), blk, 0, stream>>>(po_c, Wl_c, bl_c, out + 12 * 4096, 1024, 4096, 16 * 4096, 256);

    // layernorm in place on d_out
    ln_kernel<<<dim3(1024), blk, 0, stream>>>(out, ln_g, ln_b);
}

// Round 3
// 1077.380 us; speedup vs baseline: 2.2790x; 1.3245x over previous
//
#include <hip/hip_runtime.h>
#include <cstdint>
#include <cstddef>

typedef __attribute__((ext_vector_type(8))) short short8;
typedef __attribute__((ext_vector_type(4))) float floatx4;

__device__ __forceinline__ unsigned short f2bf(float f) {
    unsigned int u = __builtin_bit_cast(unsigned int, f);
    u += 0x7fffu + ((u >> 16) & 1u);
    return (unsigned short)(u >> 16);
}
__device__ __forceinline__ float bflo(unsigned int u) {
    return __builtin_bit_cast(float, u << 16);
}
__device__ __forceinline__ float bfhi(unsigned int u) {
    return __builtin_bit_cast(float, u & 0xffff0000u);
}
__device__ __forceinline__ short8 pack8(float4 a, float4 b) {
    short8 r;
    r[0] = (short)f2bf(a.x); r[1] = (short)f2bf(a.y);
    r[2] = (short)f2bf(a.z); r[3] = (short)f2bf(a.w);
    r[4] = (short)f2bf(b.x); r[5] = (short)f2bf(b.y);
    r[6] = (short)f2bf(b.z); r[7] = (short)f2bf(b.w);
    return r;
}

// ---------------------------------------------------------------------------
// gemm_nt_kv: C_bf16(M,N) = A_f32(M,K) @ W_f32(N,K)^T + bias. Tile 128x128x32.
// Grid (N/128, M/128). Block 256 (4 waves, each 64x64).
// ---------------------------------------------------------------------------
__global__ __launch_bounds__(256) void gemm_nt_kv(
    const float* __restrict__ A, const float* __restrict__ W,
    const float* __restrict__ bias, unsigned short* __restrict__ C,
    int K, int N)
{
    __shared__ short As[128 * 32];
    __shared__ short Bs[128 * 32];
    const int j0 = blockIdx.x * 128, i0 = blockIdx.y * 128;
    const int tid = threadIdx.x;
    const int w = tid >> 6, lane = tid & 63;
    const int quad = lane >> 4, l16 = lane & 15;
    const int moff = (w >> 1) * 64, noff = (w & 1) * 64;
    const int rS = tid >> 1, sS = (tid & 1) * 16;
    floatx4 acc[4][4] = {};

    for (int k0 = 0; k0 < K; k0 += 32) {
        const float* ga = A + (size_t)(i0 + rS) * K + k0 + sS;
        const float* gb = W + (size_t)(j0 + rS) * K + k0 + sS;
        float4 a0 = *(const float4*)(ga + 0), a1 = *(const float4*)(ga + 4);
        float4 a2 = *(const float4*)(ga + 8), a3 = *(const float4*)(ga + 12);
        float4 b0 = *(const float4*)(gb + 0), b1 = *(const float4*)(gb + 4);
        float4 b2 = *(const float4*)(gb + 8), b3 = *(const float4*)(gb + 12);
        *(short8*)&As[rS * 32 + sS + 0] = pack8(a0, a1);
        *(short8*)&As[rS * 32 + sS + 8] = pack8(a2, a3);
        *(short8*)&Bs[rS * 32 + sS + 0] = pack8(b0, b1);
        *(short8*)&Bs[rS * 32 + sS + 8] = pack8(b2, b3);
        __syncthreads();
        short8 af[4], bf[4];
#pragma unroll
        for (int r = 0; r < 4; ++r)
            af[r] = *(const short8*)&As[(moff + r * 16 + l16) * 32 + quad * 8];
#pragma unroll
        for (int c = 0; c < 4; ++c)
            bf[c] = *(const short8*)&Bs[(noff + c * 16 + l16) * 32 + quad * 8];
#pragma unroll
        for (int r = 0; r < 4; ++r)
#pragma unroll
            for (int c = 0; c < 4; ++c)
                acc[r][c] = __builtin_amdgcn_mfma_f32_16x16x32_bf16(af[r], bf[c], acc[r][c], 0, 0, 0);
        __syncthreads();
    }
#pragma unroll
    for (int r = 0; r < 4; ++r)
#pragma unroll
        for (int c = 0; c < 4; ++c) {
            int col = j0 + noff + c * 16 + l16;
            float bj = bias[col];
#pragma unroll
            for (int g = 0; g < 4; ++g) {
                int row = i0 + moff + r * 16 + quad * 4 + g;
                C[(size_t)row * N + col] = f2bf(acc[r][c][g] + bj);
            }
        }
}

// ---------------------------------------------------------------------------
// gemm_nt_sm: C_f32(64,N) (+)= A_f32(64,K[chunk]) @ W_f32(N,K)^T (+bias on kz0)
// Tile 64x128x32, split-K via blockIdx.z (atomicAdd if gridDim.z>1).
// ---------------------------------------------------------------------------
__global__ __launch_bounds__(256) void gemm_nt_sm(
    const float* __restrict__ A, const float* __restrict__ W,
    const float* __restrict__ bias, float* __restrict__ C,
    int K, int N, int Kc)
{
    __shared__ short As[64 * 32];
    __shared__ short Bs[128 * 32];
    const int j0 = blockIdx.x * 128;
    const int kz = blockIdx.z, kb = kz * Kc;
    const int tid = threadIdx.x;
    const int w = tid >> 6, lane = tid & 63;
    const int quad = lane >> 4, l16 = lane & 15;
    const int noff = w * 32;
    const int rA = tid >> 2, sA = (tid & 3) * 8;
    const int rB = tid >> 1, sB = (tid & 1) * 16;
    floatx4 acc[4][2] = {};

    for (int k0 = kb; k0 < kb + Kc; k0 += 32) {
        const float* ga = A + (size_t)rA * K + k0 + sA;
        float4 a0 = *(const float4*)(ga + 0), a1 = *(const float4*)(ga + 4);
        const float* gb = W + (size_t)(j0 + rB) * K + k0 + sB;
        float4 b0 = *(const float4*)(gb + 0), b1 = *(const float4*)(gb + 4);
        float4 b2 = *(const float4*)(gb + 8), b3 = *(const float4*)(gb + 12);
        *(short8*)&As[rA * 32 + sA] = pack8(a0, a1);
        *(short8*)&Bs[rB * 32 + sB + 0] = pack8(b0, b1);
        *(short8*)&Bs[rB * 32 + sB + 8] = pack8(b2, b3);
        __syncthreads();
        short8 af[4], bf[2];
#pragma unroll
        for (int r = 0; r < 4; ++r)
            af[r] = *(const short8*)&As[(r * 16 + l16) * 32 + quad * 8];
#pragma unroll
        for (int c = 0; c < 2; ++c)
            bf[c] = *(const short8*)&Bs[(noff + c * 16 + l16) * 32 + quad * 8];
#pragma unroll
        for (int r = 0; r < 4; ++r)
#pragma unroll
            for (int c = 0; c < 2; ++c)
                acc[r][c] = __builtin_amdgcn_mfma_f32_16x16x32_bf16(af[r], bf[c], acc[r][c], 0, 0, 0);
        __syncthreads();
    }
    const bool single = (gridDim.z == 1);
#pragma unroll
    for (int r = 0; r < 4; ++r)
#pragma unroll
        for (int c = 0; c < 2; ++c) {
            int col = j0 + noff + c * 16 + l16;
            float bj = (kz == 0) ? bias[col] : 0.f;
#pragma unroll
            for (int g = 0; g < 4; ++g) {
                int row = r * 16 + quad * 4 + g;
                float v = acc[r][c][g] + bj;
                if (single) C[(size_t)row * N + col] = v;
                else        atomicAdd(&C[(size_t)row * N + col], v);
            }
        }
}

// ---------------------------------------------------------------------------
// tcvt: W(Z,K,4096) f32 -> WT(Z,4096,K) bf16, tiled 32x32 transpose.
// Grid (K/32, 128, Z). Block 256.
// ---------------------------------------------------------------------------
__global__ __launch_bounds__(256) void tcvt(
    const float* __restrict__ in, unsigned short* __restrict__ out, int K)
{
    const int z = blockIdx.z;
    in += (size_t)z * K * 4096;
    out += (size_t)z * 4096 * K;
    const int k0 = blockIdx.x * 32, e0 = blockIdx.y * 32;
    const int tid = threadIdx.x;
    __shared__ float sh[32][33];
    {
        const int c = tid & 31, r = tid >> 5;
#pragma unroll
        for (int i = 0; i < 4; ++i)
            sh[r + 8 * i][c] = in[(size_t)(k0 + r + 8 * i) * 4096 + e0 + c];
    }
    __syncthreads();
    {
        const int e = tid >> 3, kq = (tid & 7) * 4;
        unsigned int u0 = (unsigned int)f2bf(sh[kq + 0][e]) | ((unsigned int)f2bf(sh[kq + 1][e]) << 16);
        unsigned int u1 = (unsigned int)f2bf(sh[kq + 2][e]) | ((unsigned int)f2bf(sh[kq + 3][e]) << 16);
        uint2 u = make_uint2(u0, u1);
        *(uint2*)&out[(size_t)(e0 + e) * K + k0 + kq] = u;
    }
}

// ---------------------------------------------------------------------------
// gemm_nt_lift: C_f32(64, slice) = A_f32(64,K) @ Bt_bf16(4096,K)^T + bias
// Bt/bias/C offset per slot z. Tile 64x128x32. Grid (32, 1, Z).
// ---------------------------------------------------------------------------
__global__ __launch_bounds__(256) void gemm_nt_lift(
    const float* __restrict__ A, const unsigned short* __restrict__ Bt,
    const float* __restrict__ bias, float* __restrict__ C,
    int K, int ldc)
{
    const int z = blockIdx.z;
    Bt += (size_t)z * 4096 * K;
    bias += (size_t)z * 4096;
    C += (size_t)z * 4096;

    __shared__ short As[64 * 32];
    __shared__ short Bs[128 * 32];
    const int j0 = blockIdx.x * 128;
    const int tid = threadIdx.x;
    const int w = tid >> 6, lane = tid & 63;
    const int quad = lane >> 4, l16 = lane & 15;
    const int noff = w * 32;
    const int rA = tid >> 2, sA = (tid & 3) * 8;
    const int rB = tid >> 1, sB = (tid & 1) * 16;
    floatx4 acc[4][2] = {};

    for (int k0 = 0; k0 < K; k0 += 32) {
        const float* ga = A + (size_t)rA * K + k0 + sA;
        float4 a0 = *(const float4*)(ga + 0), a1 = *(const float4*)(ga + 4);
        const unsigned short* gb = Bt + (size_t)(j0 + rB) * K + k0 + sB;
        uint4 w0 = *(const uint4*)(gb + 0);
        uint4 w1 = *(const uint4*)(gb + 8);
        *(short8*)&As[rA * 32 + sA] = pack8(a0, a1);
        *(uint4*)&Bs[rB * 32 + sB + 0] = w0;
        *(uint4*)&Bs[rB * 32 + sB + 8] = w1;
        __syncthreads();
        short8 af[4], bf[2];
#pragma unroll
        for (int r = 0; r < 4; ++r)
            af[r] = *(const short8*)&As[(r * 16 + l16) * 32 + quad * 8];
#pragma unroll
        for (int c = 0; c < 2; ++c)
            bf[c] = *(const short8*)&Bs[(noff + c * 16 + l16) * 32 + quad * 8];
#pragma unroll
        for (int r = 0; r < 4; ++r)
#pragma unroll
            for (int c = 0; c < 2; ++c)
                acc[r][c] = __builtin_amdgcn_mfma_f32_16x16x32_bf16(af[r], bf[c], acc[r][c], 0, 0, 0);
        __syncthreads();
    }
#pragma unroll
    for (int r = 0; r < 4; ++r)
#pragma unroll
        for (int c = 0; c < 2; ++c) {
            int col = j0 + noff + c * 16 + l16;
            float bj = bias[col];
#pragma unroll
            for (int g = 0; g < 4; ++g) {
                int row = r * 16 + quad * 4 + g;
                C[(size_t)row * ldc + col] = acc[r][c][g] + bj;
            }
        }
}

// ---------------------------------------------------------------------------
// attn1_bf16: one (b,h); qp f32 (B,d); kv bf16 (M,2d) rows=[k|v]; out f32.
// ---------------------------------------------------------------------------
__global__ __launch_bounds__(256) void attn1_bf16(
    const float* __restrict__ qp, const unsigned short* __restrict__ kv,
    const uint8_t* __restrict__ mask, float* __restrict__ out, int d)
{
    const int h = blockIdx.x, b = blockIdx.y;
    const int tid = threadIdx.x;
    __shared__ __align__(16) float sc[2048];
    __shared__ __align__(16) float qs[64];
    __shared__ float red[4];
    __shared__ float s_max, s_inv;

    if (tid < 64) qs[tid] = qp[(size_t)b * d + h * 64 + tid];
    __syncthreads();

    const size_t twoD = 2 * (size_t)d;
    float lmax = -1e30f;
    for (int m = tid; m < 2048; m += 256) {
        const uint4* kr = (const uint4*)(kv + (size_t)m * twoD + h * 64);
        float s = 0.f;
#pragma unroll
        for (int j = 0; j < 8; ++j) {
            uint4 u = kr[j];
            const float* q8 = qs + j * 8;
            s += bflo(u.x) * q8[0] + bfhi(u.x) * q8[1];
            s += bflo(u.y) * q8[2] + bfhi(u.y) * q8[3];
            s += bflo(u.z) * q8[4] + bfhi(u.z) * q8[5];
            s += bflo(u.w) * q8[6] + bfhi(u.w) * q8[7];
        }
        s *= 0.125f;
        if (mask[(size_t)b * 2048 + m]) s = -1e9f;
        sc[m] = s;
        lmax = fmaxf(lmax, s);
    }
#pragma unroll
    for (int off = 32; off; off >>= 1) lmax = fmaxf(lmax, __shfl_down(lmax, off));
    if ((tid & 63) == 0) red[tid >> 6] = lmax;
    __syncthreads();
    if (tid == 0) s_max = fmaxf(fmaxf(red[0], red[1]), fmaxf(red[2], red[3]));
    __syncthreads();
    const float mx = s_max;

    float lsum = 0.f;
    for (int m = tid; m < 2048; m += 256) {
        float e = expf(sc[m] - mx);
        sc[m] = e;
        lsum += e;
    }
#pragma unroll
    for (int off = 32; off; off >>= 1) lsum += __shfl_down(lsum, off);
    if ((tid & 63) == 0) red[tid >> 6] = lsum;
    __syncthreads();
    if (tid == 0) s_inv = 1.f / (red[0] + red[1] + red[2] + red[3]);
    __syncthreads();
    const float inv = s_inv;

    const int lane = tid & 63, grp = tid >> 6;
    float acc = 0.f;
    for (int m = grp; m < 2048; m += 4) {
        unsigned int u = kv[(size_t)m * twoD + d + h * 64 + lane];
        acc += sc[m] * bflo(u);
    }
    __syncthreads();
    sc[grp * 64 + lane] = acc;
    __syncthreads();
    if (grp == 0) {
        float o = (sc[lane] + sc[64 + lane] + sc[128 + lane] + sc[192 + lane]) * inv;
        out[(size_t)b * d + h * 64 + lane] = o;
    }
}

// ---------------------------------------------------------------------------
__global__ __launch_bounds__(256) void ln_kernel(
    float* __restrict__ x, const float* __restrict__ g, const float* __restrict__ bb)
{
    const int row = blockIdx.x;
    float* xr = x + (size_t)row * 4096;
    const int tid = threadIdx.x;
    float v[16];
    float sum = 0.f, sumsq = 0.f;
#pragma unroll
    for (int i = 0; i < 16; ++i) {
        v[i] = xr[tid + i * 256];
        sum += v[i];
        sumsq += v[i] * v[i];
    }
    __shared__ float rs[4], rq[4];
#pragma unroll
    for (int off = 32; off; off >>= 1) {
        sum += __shfl_down(sum, off);
        sumsq += __shfl_down(sumsq, off);
    }
    if ((tid & 63) == 0) { rs[tid >> 6] = sum; rq[tid >> 6] = sumsq; }
    __syncthreads();
    const float ts = rs[0] + rs[1] + rs[2] + rs[3];
    const float tq = rq[0] + rq[1] + rq[2] + rq[3];
    const float mu = ts * (1.f / 4096.f);
    const float var = tq * (1.f / 4096.f) - mu * mu;
    const float r = rsqrtf(var + 1e-5f);
#pragma unroll
    for (int i = 0; i < 16; ++i) {
        int e = tid + i * 256;
        xr[e] = (v[i] - mu) * r * g[e] + bb[e];
    }
}

// ---------------------------------------------------------------------------
extern "C" void kernel_launch(void* const* d_in, const int* in_sizes, int n_in,
                              void* d_out, int out_size, void* d_ws, size_t ws_size,
                              hipStream_t stream)
{
    const float*   hs     = (const float*)d_in[0];
    const float*   fib_t  = (const float*)d_in[1];
    const float*   fib_p  = (const float*)d_in[2];
    const float*   fib_c  = (const float*)d_in[3];
    const uint8_t* mask   = (const uint8_t*)d_in[4];
    const float* Wq_t   = (const float*)d_in[5];  const float* bq_t   = (const float*)d_in[6];
    const float* Wq_p   = (const float*)d_in[7];  const float* bq_p   = (const float*)d_in[8];
    const float* Wq_c   = (const float*)d_in[9];  const float* bq_c   = (const float*)d_in[10];
    const float* Wqkv_t = (const float*)d_in[11]; const float* bqkv_t = (const float*)d_in[12];
    const float* Wo_t   = (const float*)d_in[13]; const float* bo_t   = (const float*)d_in[14];
    const float* Wqkv_p = (const float*)d_in[15]; const float* bqkv_p = (const float*)d_in[16];
    const float* Wo_p   = (const float*)d_in[17]; const float* bo_p   = (const float*)d_in[18];
    const float* Wqkv_c = (const float*)d_in[19]; const float* bqkv_c = (const float*)d_in[20];
    const float* Wo_c   = (const float*)d_in[21]; const float* bo_c   = (const float*)d_in[22];
    const float* Wl_t   = (const float*)d_in[23]; const float* bl_t   = (const float*)d_in[24];
    const float* Wl_p   = (const float*)d_in[25]; const float* bl_p   = (const float*)d_in[26];
    const float* Wl_c   = (const float*)d_in[27]; const float* bl_c   = (const float*)d_in[28];
    const float* ln_g   = (const float*)d_in[29]; const float* ln_b   = (const float*)d_in[30];

    char* wsb = (char*)d_ws;
    float* q_t  = (float*)wsb; wsb += 64 * 256 * 4;
    float* q_p  = (float*)wsb; wsb += 64 * 512 * 4;
    float* q_c  = (float*)wsb; wsb += 64 * 1024 * 4;
    float* qp_t = (float*)wsb; wsb += 64 * 256 * 4;
    float* qp_p = (float*)wsb; wsb += 64 * 512 * 4;
    float* qp_c = (float*)wsb; wsb += 64 * 1024 * 4;
    float* po_t = (float*)wsb; wsb += 64 * 256 * 4;
    float* po_p = (float*)wsb; wsb += 64 * 512 * 4;
    float* po_c = (float*)wsb; wsb += 64 * 1024 * 4;
    size_t zbytes = (size_t)(wsb - (char*)d_ws);       // split-K targets, zeroed
    float* o_t  = (float*)wsb; wsb += 64 * 256 * 4;
    float* o_p  = (float*)wsb; wsb += 64 * 512 * 4;
    float* o_c  = (float*)wsb; wsb += 64 * 1024 * 4;
    unsigned short* kv_t = (unsigned short*)wsb; wsb += 2048 * 512 * 2;
    unsigned short* kv_p = (unsigned short*)wsb; wsb += 2048 * 1024 * 2;
    unsigned short* kv_c = (unsigned short*)wsb; wsb += 2048 * 2048 * 2;
    unsigned short* wlT_t = (unsigned short*)wsb; wsb += (size_t)4 * 4096 * 256 * 2;
    unsigned short* wlT_p = (unsigned short*)wsb; wsb += (size_t)8 * 4096 * 512 * 2;
    unsigned short* wlT_c = (unsigned short*)wsb; wsb += (size_t)4 * 4096 * 1024 * 2;
    float* out = (float*)d_out;

    const dim3 blk(256);

    hipMemsetAsync(d_ws, 0, zbytes, stream);

    // bundle query heads (split-K 8)
    gemm_nt_sm<<<dim3(2, 1, 8), blk, 0, stream>>>(hs, Wq_t, bq_t, q_t, 4096, 256, 512);
    gemm_nt_sm<<<dim3(4, 1, 8), blk, 0, stream>>>(hs, Wq_p, bq_p, q_p, 4096, 512, 512);
    gemm_nt_sm<<<dim3(8, 1, 8), blk, 0, stream>>>(hs, Wq_c, bq_c, q_c, 4096, 1024, 512);

    // kv projections -> bf16
    gemm_nt_kv<<<dim3(4, 16),  blk, 0, stream>>>(fib_t, Wqkv_t + 256 * 256,   bqkv_t + 256,  kv_t, 256, 512);
    gemm_nt_kv<<<dim3(8, 16),  blk, 0, stream>>>(fib_p, Wqkv_p + 512 * 512,   bqkv_p + 512,  kv_p, 512, 1024);
    gemm_nt_kv<<<dim3(16, 16), blk, 0, stream>>>(fib_c, Wqkv_c + 1024 * 1024, bqkv_c + 1024, kv_c, 1024, 2048);

    // lift weight transpose+convert (independent; HBM-bound)
    tcvt<<<dim3(8, 128, 4),  blk, 0, stream>>>(Wl_t, wlT_t, 256);
    tcvt<<<dim3(16, 128, 8), blk, 0, stream>>>(Wl_p, wlT_p, 512);
    tcvt<<<dim3(32, 128, 4), blk, 0, stream>>>(Wl_c, wlT_c, 1024);

    // q in-proj
    gemm_nt_sm<<<dim3(2, 1, 2), blk, 0, stream>>>(q_t, Wqkv_t, bqkv_t, qp_t, 256, 256, 128);
    gemm_nt_sm<<<dim3(4, 1, 2), blk, 0, stream>>>(q_p, Wqkv_p, bqkv_p, qp_p, 512, 512, 256);
    gemm_nt_sm<<<dim3(8, 1, 4), blk, 0, stream>>>(q_c, Wqkv_c, bqkv_c, qp_c, 1024, 1024, 256);

    // attention
    attn1_bf16<<<dim3(4, 64),  blk, 0, stream>>>(qp_t, kv_t, mask, o_t, 256);
    attn1_bf16<<<dim3(8, 64),  blk, 0, stream>>>(qp_p, kv_p, mask, o_p, 512);
    attn1_bf16<<<dim3(16, 64), blk, 0, stream>>>(qp_c, kv_c, mask, o_c, 1024);

    // out proj
    gemm_nt_sm<<<dim3(2, 1, 2), blk, 0, stream>>>(o_t, Wo_t, bo_t, po_t, 256, 256, 128);
    gemm_nt_sm<<<dim3(4, 1, 2), blk, 0, stream>>>(o_p, Wo_p, bo_p, po_p, 512, 512, 256);
    gemm_nt_sm<<<dim3(8, 1, 4), blk, 0, stream>>>(o_c, Wo_c, bo_c, po_c, 1024, 1024, 256);

    // lifts -> d_out directly (prefix layout (64, 16, 4096))
    gemm_nt_lift<<<dim3(32, 1, 4), blk, 0, stream>>>(po_t, wlT_t, bl_t, out + 0 * 4096,  256,  16 * 4096);
    gemm_nt_lift<<<dim3(32, 1, 8), blk, 0, stream>>>(po_p, wlT_p, bl_p, out + 4 * 4096,  512,  16 * 4096);
    gemm_nt_lift<<<dim3(32, 1, 4), blk, 0, stream>>>(po_c, wlT_c, bl_c, out + 12 * 4096, 1024, 16 * 4096);

    // layernorm in place
    ln_kernel<<<dim3(1024), blk, 0, stream>>>(out, ln_g, ln_b);
}

// Round 4
// 691.760 us; speedup vs baseline: 3.5495x; 1.5574x over previous
//
#include <hip/hip_runtime.h>
#include <cstdint>
#include <cstddef>

typedef __attribute__((ext_vector_type(8))) short short8;
typedef __attribute__((ext_vector_type(4))) float floatx4;

__device__ __forceinline__ unsigned short f2bf(float f) {
    unsigned int u = __builtin_bit_cast(unsigned int, f);
    u += 0x7fffu + ((u >> 16) & 1u);
    return (unsigned short)(u >> 16);
}
__device__ __forceinline__ float bflo(unsigned int u) {
    return __builtin_bit_cast(float, u << 16);
}
__device__ __forceinline__ short8 pack8(float4 a, float4 b) {
    short8 r;
    r[0] = (short)f2bf(a.x); r[1] = (short)f2bf(a.y);
    r[2] = (short)f2bf(a.z); r[3] = (short)f2bf(a.w);
    r[4] = (short)f2bf(b.x); r[5] = (short)f2bf(b.y);
    r[6] = (short)f2bf(b.z); r[7] = (short)f2bf(b.w);
    return r;
}

// ---------------------------------------------------------------------------
// gemm_nt_kv: C_bf16(M,N) = A_f32(M,K) @ W_f32(N,K)^T + bias. Tile 128x128x32.
// ---------------------------------------------------------------------------
__global__ __launch_bounds__(256) void gemm_nt_kv(
    const float* __restrict__ A, const float* __restrict__ W,
    const float* __restrict__ bias, unsigned short* __restrict__ C,
    int K, int N)
{
    __shared__ short As[128 * 32];
    __shared__ short Bs[128 * 32];
    const int j0 = blockIdx.x * 128, i0 = blockIdx.y * 128;
    const int tid = threadIdx.x;
    const int w = tid >> 6, lane = tid & 63;
    const int quad = lane >> 4, l16 = lane & 15;
    const int moff = (w >> 1) * 64, noff = (w & 1) * 64;
    const int rS = tid >> 1, sS = (tid & 1) * 16;
    floatx4 acc[4][4] = {};

    for (int k0 = 0; k0 < K; k0 += 32) {
        const float* ga = A + (size_t)(i0 + rS) * K + k0 + sS;
        const float* gb = W + (size_t)(j0 + rS) * K + k0 + sS;
        float4 a0 = *(const float4*)(ga + 0), a1 = *(const float4*)(ga + 4);
        float4 a2 = *(const float4*)(ga + 8), a3 = *(const float4*)(ga + 12);
        float4 b0 = *(const float4*)(gb + 0), b1 = *(const float4*)(gb + 4);
        float4 b2 = *(const float4*)(gb + 8), b3 = *(const float4*)(gb + 12);
        *(short8*)&As[rS * 32 + sS + 0] = pack8(a0, a1);
        *(short8*)&As[rS * 32 + sS + 8] = pack8(a2, a3);
        *(short8*)&Bs[rS * 32 + sS + 0] = pack8(b0, b1);
        *(short8*)&Bs[rS * 32 + sS + 8] = pack8(b2, b3);
        __syncthreads();
        short8 af[4], bf[4];
#pragma unroll
        for (int r = 0; r < 4; ++r)
            af[r] = *(const short8*)&As[(moff + r * 16 + l16) * 32 + quad * 8];
#pragma unroll
        for (int c = 0; c < 4; ++c)
            bf[c] = *(const short8*)&Bs[(noff + c * 16 + l16) * 32 + quad * 8];
#pragma unroll
        for (int r = 0; r < 4; ++r)
#pragma unroll
            for (int c = 0; c < 4; ++c)
                acc[r][c] = __builtin_amdgcn_mfma_f32_16x16x32_bf16(af[r], bf[c], acc[r][c], 0, 0, 0);
        __syncthreads();
    }
#pragma unroll
    for (int r = 0; r < 4; ++r)
#pragma unroll
        for (int c = 0; c < 4; ++c) {
            int col = j0 + noff + c * 16 + l16;
            float bj = bias[col];
#pragma unroll
            for (int g = 0; g < 4; ++g) {
                int row = i0 + moff + r * 16 + quad * 4 + g;
                C[(size_t)row * N + col] = f2bf(acc[r][c][g] + bj);
            }
        }
}

// ---------------------------------------------------------------------------
// gemm_nt_sm: C_f32(64,N) (+)= A_f32(64,K[chunk]) @ W_f32(N,K)^T (+bias on kz0)
// ---------------------------------------------------------------------------
__global__ __launch_bounds__(256) void gemm_nt_sm(
    const float* __restrict__ A, const float* __restrict__ W,
    const float* __restrict__ bias, float* __restrict__ C,
    int K, int N, int Kc)
{
    __shared__ short As[64 * 32];
    __shared__ short Bs[128 * 32];
    const int j0 = blockIdx.x * 128;
    const int kz = blockIdx.z, kb = kz * Kc;
    const int tid = threadIdx.x;
    const int w = tid >> 6, lane = tid & 63;
    const int quad = lane >> 4, l16 = lane & 15;
    const int noff = w * 32;
    const int rA = tid >> 2, sA = (tid & 3) * 8;
    const int rB = tid >> 1, sB = (tid & 1) * 16;
    floatx4 acc[4][2] = {};

    for (int k0 = kb; k0 < kb + Kc; k0 += 32) {
        const float* ga = A + (size_t)rA * K + k0 + sA;
        float4 a0 = *(const float4*)(ga + 0), a1 = *(const float4*)(ga + 4);
        const float* gb = W + (size_t)(j0 + rB) * K + k0 + sB;
        float4 b0 = *(const float4*)(gb + 0), b1 = *(const float4*)(gb + 4);
        float4 b2 = *(const float4*)(gb + 8), b3 = *(const float4*)(gb + 12);
        *(short8*)&As[rA * 32 + sA] = pack8(a0, a1);
        *(short8*)&Bs[rB * 32 + sB + 0] = pack8(b0, b1);
        *(short8*)&Bs[rB * 32 + sB + 8] = pack8(b2, b3);
        __syncthreads();
        short8 af[4], bf[2];
#pragma unroll
        for (int r = 0; r < 4; ++r)
            af[r] = *(const short8*)&As[(r * 16 + l16) * 32 + quad * 8];
#pragma unroll
        for (int c = 0; c < 2; ++c)
            bf[c] = *(const short8*)&Bs[(noff + c * 16 + l16) * 32 + quad * 8];
#pragma unroll
        for (int r = 0; r < 4; ++r)
#pragma unroll
            for (int c = 0; c < 2; ++c)
                acc[r][c] = __builtin_amdgcn_mfma_f32_16x16x32_bf16(af[r], bf[c], acc[r][c], 0, 0, 0);
        __syncthreads();
    }
    const bool single = (gridDim.z == 1);
#pragma unroll
    for (int r = 0; r < 4; ++r)
#pragma unroll
        for (int c = 0; c < 2; ++c) {
            int col = j0 + noff + c * 16 + l16;
            float bj = (kz == 0) ? bias[col] : 0.f;
#pragma unroll
            for (int g = 0; g < 4; ++g) {
                int row = r * 16 + quad * 4 + g;
                float v = acc[r][c][g] + bj;
                if (single) C[(size_t)row * N + col] = v;
                else        atomicAdd(&C[(size_t)row * N + col], v);
            }
        }
}

// ---------------------------------------------------------------------------
// tcvt: W(Z,K,4096) f32 -> WT(Z,4096,K) bf16
// ---------------------------------------------------------------------------
__global__ __launch_bounds__(256) void tcvt(
    const float* __restrict__ in, unsigned short* __restrict__ out, int K)
{
    const int z = blockIdx.z;
    in += (size_t)z * K * 4096;
    out += (size_t)z * 4096 * K;
    const int k0 = blockIdx.x * 32, e0 = blockIdx.y * 32;
    const int tid = threadIdx.x;
    __shared__ float sh[32][33];
    {
        const int c = tid & 31, r = tid >> 5;
#pragma unroll
        for (int i = 0; i < 4; ++i)
            sh[r + 8 * i][c] = in[(size_t)(k0 + r + 8 * i) * 4096 + e0 + c];
    }
    __syncthreads();
    {
        const int e = tid >> 3, kq = (tid & 7) * 4;
        unsigned int u0 = (unsigned int)f2bf(sh[kq + 0][e]) | ((unsigned int)f2bf(sh[kq + 1][e]) << 16);
        unsigned int u1 = (unsigned int)f2bf(sh[kq + 2][e]) | ((unsigned int)f2bf(sh[kq + 3][e]) << 16);
        uint2 u = make_uint2(u0, u1);
        *(uint2*)&out[(size_t)(e0 + e) * K + k0 + kq] = u;
    }
}

// ---------------------------------------------------------------------------
// gemm_nt_lift: C_f32(64, slice) = A_f32(64,K) @ Bt_bf16(4096,K)^T + bias
// ---------------------------------------------------------------------------
__global__ __launch_bounds__(256) void gemm_nt_lift(
    const float* __restrict__ A, const unsigned short* __restrict__ Bt,
    const float* __restrict__ bias, float* __restrict__ C,
    int K, int ldc)
{
    const int z = blockIdx.z;
    Bt += (size_t)z * 4096 * K;
    bias += (size_t)z * 4096;
    C += (size_t)z * 4096;

    __shared__ short As[64 * 32];
    __shared__ short Bs[128 * 32];
    const int j0 = blockIdx.x * 128;
    const int tid = threadIdx.x;
    const int w = tid >> 6, lane = tid & 63;
    const int quad = lane >> 4, l16 = lane & 15;
    const int noff = w * 32;
    const int rA = tid >> 2, sA = (tid & 3) * 8;
    const int rB = tid >> 1, sB = (tid & 1) * 16;
    floatx4 acc[4][2] = {};

    for (int k0 = 0; k0 < K; k0 += 32) {
        const float* ga = A + (size_t)rA * K + k0 + sA;
        float4 a0 = *(const float4*)(ga + 0), a1 = *(const float4*)(ga + 4);
        const unsigned short* gb = Bt + (size_t)(j0 + rB) * K + k0 + sB;
        uint4 w0 = *(const uint4*)(gb + 0);
        uint4 w1 = *(const uint4*)(gb + 8);
        *(short8*)&As[rA * 32 + sA] = pack8(a0, a1);
        *(uint4*)&Bs[rB * 32 + sB + 0] = w0;
        *(uint4*)&Bs[rB * 32 + sB + 8] = w1;
        __syncthreads();
        short8 af[4], bf[2];
#pragma unroll
        for (int r = 0; r < 4; ++r)
            af[r] = *(const short8*)&As[(r * 16 + l16) * 32 + quad * 8];
#pragma unroll
        for (int c = 0; c < 2; ++c)
            bf[c] = *(const short8*)&Bs[(noff + c * 16 + l16) * 32 + quad * 8];
#pragma unroll
        for (int r = 0; r < 4; ++r)
#pragma unroll
            for (int c = 0; c < 2; ++c)
                acc[r][c] = __builtin_amdgcn_mfma_f32_16x16x32_bf16(af[r], bf[c], acc[r][c], 0, 0, 0);
        __syncthreads();
    }
#pragma unroll
    for (int r = 0; r < 4; ++r)
#pragma unroll
        for (int c = 0; c < 2; ++c) {
            int col = j0 + noff + c * 16 + l16;
            float bj = bias[col];
#pragma unroll
            for (int g = 0; g < 4; ++g) {
                int row = r * 16 + quad * 4 + g;
                C[(size_t)row * ldc + col] = acc[r][c][g] + bj;
            }
        }
}

// ---------------------------------------------------------------------------
// qk_mfma: S(64b x 128m tile) = 0.125 * Q_h @ K_h^T  for head h of one bundle.
// qp f32 (64, d); kv bf16 (M, 2d); S f32 (nh*64, 2048) pre-offset per bundle.
// Grid (16 m-tiles, nh). Block 256 (4 waves, each 64x32 of the tile).
// ---------------------------------------------------------------------------
__global__ __launch_bounds__(256) void qk_mfma(
    const float* __restrict__ qp, const unsigned short* __restrict__ kv,
    float* __restrict__ S, int d)
{
    __shared__ short As[64 * 72];   // Q tile, padded stride 72 (2-way banks)
    __shared__ short Bs[128 * 72];  // K tile
    const int h = blockIdx.y;
    const int j0 = blockIdx.x * 128;
    const int tid = threadIdx.x;
    const int w = tid >> 6, lane = tid & 63;
    const int quad = lane >> 4, l16 = lane & 15;
    const int noff = w * 32;
    const int twoD = 2 * d;

    {   // stage Q: thread t -> row b=t>>2, k-chunk (t&3)*16
        const int b = tid >> 2, kc = (tid & 3) * 16;
        const float* ga = qp + (size_t)b * d + h * 64 + kc;
        float4 a0 = *(const float4*)(ga + 0), a1 = *(const float4*)(ga + 4);
        float4 a2 = *(const float4*)(ga + 8), a3 = *(const float4*)(ga + 12);
        *(short8*)&As[b * 72 + kc + 0] = pack8(a0, a1);
        *(short8*)&As[b * 72 + kc + 8] = pack8(a2, a3);
    }
    {   // stage K: thread t -> row m=t>>1, half (t&1)*32
        const int m = tid >> 1, hf = (tid & 1) * 32;
        const unsigned short* gb = kv + (size_t)(j0 + m) * twoD + h * 64 + hf;
        uint4 b0 = *(const uint4*)(gb + 0),  b1 = *(const uint4*)(gb + 8);
        uint4 b2 = *(const uint4*)(gb + 16), b3 = *(const uint4*)(gb + 24);
        *(uint4*)&Bs[m * 72 + hf + 0]  = b0;
        *(uint4*)&Bs[m * 72 + hf + 8]  = b1;
        *(uint4*)&Bs[m * 72 + hf + 16] = b2;
        *(uint4*)&Bs[m * 72 + hf + 24] = b3;
    }
    __syncthreads();

    floatx4 acc[4][2] = {};
#pragma unroll
    for (int k0 = 0; k0 < 64; k0 += 32) {
        short8 af[4], bfr[2];
#pragma unroll
        for (int r = 0; r < 4; ++r)
            af[r] = *(const short8*)&As[(r * 16 + l16) * 72 + k0 + quad * 8];
#pragma unroll
        for (int c = 0; c < 2; ++c)
            bfr[c] = *(const short8*)&Bs[(noff + c * 16 + l16) * 72 + k0 + quad * 8];
#pragma unroll
        for (int r = 0; r < 4; ++r)
#pragma unroll
            for (int c = 0; c < 2; ++c)
                acc[r][c] = __builtin_amdgcn_mfma_f32_16x16x32_bf16(af[r], bfr[c], acc[r][c], 0, 0, 0);
    }
#pragma unroll
    for (int r = 0; r < 4; ++r)
#pragma unroll
        for (int c = 0; c < 2; ++c) {
            int col = j0 + noff + c * 16 + l16;
#pragma unroll
            for (int g = 0; g < 4; ++g) {
                int row = r * 16 + quad * 4 + g;   // b index
                S[((size_t)h * 64 + row) * 2048 + col] = acc[r][c][g] * 0.125f;
            }
        }
}

// ---------------------------------------------------------------------------
// softmax_pv: one (h,b): softmax over S row (2048), then P @ V_h -> o[b, h*64+hd].
// Grid (nh, 64). Block 256 = 4 waves; lane = hd, waves split m.
// ---------------------------------------------------------------------------
__global__ __launch_bounds__(256) void softmax_pv(
    const float* __restrict__ S, const unsigned short* __restrict__ kv,
    const uint8_t* __restrict__ mask, float* __restrict__ o, int d)
{
    const int h = blockIdx.x, b = blockIdx.y;
    const int tid = threadIdx.x;
    __shared__ __align__(16) float sc[2048];
    __shared__ float red[4];
    __shared__ float part[4][64];
    __shared__ float s_max, s_sum;

    const float* Sr = S + ((size_t)h * 64 + b) * 2048;
    const uint8_t* mr = mask + (size_t)b * 2048;

    float lmax = -1e30f;
    for (int m = tid; m < 2048; m += 256) {
        float s = Sr[m];
        if (mr[m]) s = -1e9f;
        sc[m] = s;
        lmax = fmaxf(lmax, s);
    }
#pragma unroll
    for (int off = 32; off; off >>= 1) lmax = fmaxf(lmax, __shfl_down(lmax, off));
    if ((tid & 63) == 0) red[tid >> 6] = lmax;
    __syncthreads();
    if (tid == 0) s_max = fmaxf(fmaxf(red[0], red[1]), fmaxf(red[2], red[3]));
    __syncthreads();
    const float mx = s_max;

    float lsum = 0.f;
    for (int m = tid; m < 2048; m += 256) {
        float e = __expf(sc[m] - mx);
        sc[m] = e;
        lsum += e;
    }
#pragma unroll
    for (int off = 32; off; off >>= 1) lsum += __shfl_down(lsum, off);
    if ((tid & 63) == 0) red[tid >> 6] = lsum;
    __syncthreads();
    if (tid == 0) s_sum = red[0] + red[1] + red[2] + red[3];
    __syncthreads();

    const int lane = tid & 63, w = tid >> 6;
    const int twoD = 2 * d;
    const unsigned short* vcol = kv + d + h * 64 + lane;
    float acc = 0.f;
    const int m0 = w * 512;
#pragma unroll 1
    for (int m = m0; m < m0 + 512; m += 8) {
#pragma unroll
        for (int j = 0; j < 8; ++j)
            acc += sc[m + j] * bflo((unsigned int)vcol[(size_t)(m + j) * twoD]);
    }
    part[w][lane] = acc;
    __syncthreads();
    if (tid < 64) {
        float r = (part[0][tid] + part[1][tid] + part[2][tid] + part[3][tid]) / s_sum;
        o[(size_t)b * d + h * 64 + tid] = r;
    }
}

// ---------------------------------------------------------------------------
__global__ __launch_bounds__(256) void ln_kernel(
    float* __restrict__ x, const float* __restrict__ g, const float* __restrict__ bb)
{
    const int row = blockIdx.x;
    float* xr = x + (size_t)row * 4096;
    const int tid = threadIdx.x;
    float v[16];
    float sum = 0.f, sumsq = 0.f;
#pragma unroll
    for (int i = 0; i < 16; ++i) {
        v[i] = xr[tid + i * 256];
        sum += v[i];
        sumsq += v[i] * v[i];
    }
    __shared__ float rs[4], rq[4];
#pragma unroll
    for (int off = 32; off; off >>= 1) {
        sum += __shfl_down(sum, off);
        sumsq += __shfl_down(sumsq, off);
    }
    if ((tid & 63) == 0) { rs[tid >> 6] = sum; rq[tid >> 6] = sumsq; }
    __syncthreads();
    const float ts = rs[0] + rs[1] + rs[2] + rs[3];
    const float tq = rq[0] + rq[1] + rq[2] + rq[3];
    const float mu = ts * (1.f / 4096.f);
    const float var = tq * (1.f / 4096.f) - mu * mu;
    const float r = rsqrtf(var + 1e-5f);
#pragma unroll
    for (int i = 0; i < 16; ++i) {
        int e = tid + i * 256;
        xr[e] = (v[i] - mu) * r * g[e] + bb[e];
    }
}

// ---------------------------------------------------------------------------
extern "C" void kernel_launch(void* const* d_in, const int* in_sizes, int n_in,
                              void* d_out, int out_size, void* d_ws, size_t ws_size,
                              hipStream_t stream)
{
    const float*   hs     = (const float*)d_in[0];
    const float*   fib_t  = (const float*)d_in[1];
    const float*   fib_p  = (const float*)d_in[2];
    const float*   fib_c  = (const float*)d_in[3];
    const uint8_t* mask   = (const uint8_t*)d_in[4];
    const float* Wq_t   = (const float*)d_in[5];  const float* bq_t   = (const float*)d_in[6];
    const float* Wq_p   = (const float*)d_in[7];  const float* bq_p   = (const float*)d_in[8];
    const float* Wq_c   = (const float*)d_in[9];  const float* bq_c   = (const float*)d_in[10];
    const float* Wqkv_t = (const float*)d_in[11]; const float* bqkv_t = (const float*)d_in[12];
    const float* Wo_t   = (const float*)d_in[13]; const float* bo_t   = (const float*)d_in[14];
    const float* Wqkv_p = (const float*)d_in[15]; const float* bqkv_p = (const float*)d_in[16];
    const float* Wo_p   = (const float*)d_in[17]; const float* bo_p   = (const float*)d_in[18];
    const float* Wqkv_c = (const float*)d_in[19]; const float* bqkv_c = (const float*)d_in[20];
    const float* Wo_c   = (const float*)d_in[21]; const float* bo_c   = (const float*)d_in[22];
    const float* Wl_t   = (const float*)d_in[23]; const float* bl_t   = (const float*)d_in[24];
    const float* Wl_p   = (const float*)d_in[25]; const float* bl_p   = (const float*)d_in[26];
    const float* Wl_c   = (const float*)d_in[27]; const float* bl_c   = (const float*)d_in[28];
    const float* ln_g   = (const float*)d_in[29]; const float* ln_b   = (const float*)d_in[30];

    char* wsb = (char*)d_ws;
    float* q_t  = (float*)wsb; wsb += 64 * 256 * 4;
    float* q_p  = (float*)wsb; wsb += 64 * 512 * 4;
    float* q_c  = (float*)wsb; wsb += 64 * 1024 * 4;
    float* qp_t = (float*)wsb; wsb += 64 * 256 * 4;
    float* qp_p = (float*)wsb; wsb += 64 * 512 * 4;
    float* qp_c = (float*)wsb; wsb += 64 * 1024 * 4;
    float* po_t = (float*)wsb; wsb += 64 * 256 * 4;
    float* po_p = (float*)wsb; wsb += 64 * 512 * 4;
    float* po_c = (float*)wsb; wsb += 64 * 1024 * 4;
    size_t zbytes = (size_t)(wsb - (char*)d_ws);       // split-K targets, zeroed
    float* o_t  = (float*)wsb; wsb += 64 * 256 * 4;
    float* o_p  = (float*)wsb; wsb += 64 * 512 * 4;
    float* o_c  = (float*)wsb; wsb += 64 * 1024 * 4;
    unsigned short* kv_t = (unsigned short*)wsb; wsb += 2048 * 512 * 2;
    unsigned short* kv_p = (unsigned short*)wsb; wsb += 2048 * 1024 * 2;
    unsigned short* kv_c = (unsigned short*)wsb; wsb += 2048 * 2048 * 2;
    unsigned short* wlT_t = (unsigned short*)wsb; wsb += (size_t)4 * 4096 * 256 * 2;
    unsigned short* wlT_p = (unsigned short*)wsb; wsb += (size_t)8 * 4096 * 512 * 2;
    unsigned short* wlT_c = (unsigned short*)wsb; wsb += (size_t)4 * 4096 * 1024 * 2;
    float* S_t = (float*)wsb; wsb += (size_t)4  * 64 * 2048 * 4;   // scores f32
    float* S_p = (float*)wsb; wsb += (size_t)8  * 64 * 2048 * 4;
    float* S_c = (float*)wsb; wsb += (size_t)16 * 64 * 2048 * 4;
    float* out = (float*)d_out;

    const dim3 blk(256);

    hipMemsetAsync(d_ws, 0, zbytes, stream);

    // bundle query heads (split-K 8)
    gemm_nt_sm<<<dim3(2, 1, 8), blk, 0, stream>>>(hs, Wq_t, bq_t, q_t, 4096, 256, 512);
    gemm_nt_sm<<<dim3(4, 1, 8), blk, 0, stream>>>(hs, Wq_p, bq_p, q_p, 4096, 512, 512);
    gemm_nt_sm<<<dim3(8, 1, 8), blk, 0, stream>>>(hs, Wq_c, bq_c, q_c, 4096, 1024, 512);

    // kv projections -> bf16
    gemm_nt_kv<<<dim3(4, 16),  blk, 0, stream>>>(fib_t, Wqkv_t + 256 * 256,   bqkv_t + 256,  kv_t, 256, 512);
    gemm_nt_kv<<<dim3(8, 16),  blk, 0, stream>>>(fib_p, Wqkv_p + 512 * 512,   bqkv_p + 512,  kv_p, 512, 1024);
    gemm_nt_kv<<<dim3(16, 16), blk, 0, stream>>>(fib_c, Wqkv_c + 1024 * 1024, bqkv_c + 1024, kv_c, 1024, 2048);

    // lift weight transpose+convert (independent)
    tcvt<<<dim3(8, 128, 4),  blk, 0, stream>>>(Wl_t, wlT_t, 256);
    tcvt<<<dim3(16, 128, 8), blk, 0, stream>>>(Wl_p, wlT_p, 512);
    tcvt<<<dim3(32, 128, 4), blk, 0, stream>>>(Wl_c, wlT_c, 1024);

    // q in-proj
    gemm_nt_sm<<<dim3(2, 1, 2), blk, 0, stream>>>(q_t, Wqkv_t, bqkv_t, qp_t, 256, 256, 128);
    gemm_nt_sm<<<dim3(4, 1, 2), blk, 0, stream>>>(q_p, Wqkv_p, bqkv_p, qp_p, 512, 512, 256);
    gemm_nt_sm<<<dim3(8, 1, 4), blk, 0, stream>>>(q_c, Wqkv_c, bqkv_c, qp_c, 1024, 1024, 256);

    // attention: QK^T via MFMA, then fused softmax+PV
    qk_mfma<<<dim3(16, 4),  blk, 0, stream>>>(qp_t, kv_t, S_t, 256);
    qk_mfma<<<dim3(16, 8),  blk, 0, stream>>>(qp_p, kv_p, S_p, 512);
    qk_mfma<<<dim3(16, 16), blk, 0, stream>>>(qp_c, kv_c, S_c, 1024);

    softmax_pv<<<dim3(4, 64),  blk, 0, stream>>>(S_t, kv_t, mask, o_t, 256);
    softmax_pv<<<dim3(8, 64),  blk, 0, stream>>>(S_p, kv_p, mask, o_p, 512);
    softmax_pv<<<dim3(16, 64), blk, 0, stream>>>(S_c, kv_c, mask, o_c, 1024);

    // out proj
    gemm_nt_sm<<<dim3(2, 1, 2), blk, 0, stream>>>(o_t, Wo_t, bo_t, po_t, 256, 256, 128);
    gemm_nt_sm<<<dim3(4, 1, 2), blk, 0, stream>>>(o_p, Wo_p, bo_p, po_p, 512, 512, 256);
    gemm_nt_sm<<<dim3(8, 1, 4), blk, 0, stream>>>(o_c, Wo_c, bo_c, po_c, 1024, 1024, 256);

    // lifts -> d_out directly (prefix layout (64, 16, 4096))
    gemm_nt_lift<<<dim3(32, 1, 4), blk, 0, stream>>>(po_t, wlT_t, bl_t, out + 0 * 4096,  256,  16 * 4096);
    gemm_nt_lift<<<dim3(32, 1, 8), blk, 0, stream>>>(po_p, wlT_p, bl_p, out + 4 * 4096,  512,  16 * 4096);
    gemm_nt_lift<<<dim3(32, 1, 4), blk, 0, stream>>>(po_c, wlT_c, bl_c, out + 12 * 4096, 1024, 16 * 4096);

    // layernorm in place
    ln_kernel<<<dim3(1024), blk, 0, stream>>>(out, ln_g, ln_b);
}

// Round 5
// 396.028 us; speedup vs baseline: 6.2000x; 1.7467x over previous
//
#include <hip/hip_runtime.h>
#include <cstdint>
#include <cstddef>

typedef __attribute__((ext_vector_type(8))) short short8;
typedef __attribute__((ext_vector_type(4))) float floatx4;

__device__ __forceinline__ unsigned short f2bf(float f) {
    unsigned int u = __builtin_bit_cast(unsigned int, f);
    u += 0x7fffu + ((u >> 16) & 1u);
    return (unsigned short)(u >> 16);
}
__device__ __forceinline__ float bflo(unsigned int u) {
    return __builtin_bit_cast(float, u << 16);
}
__device__ __forceinline__ short8 pack8(float4 a, float4 b) {
    short8 r;
    r[0] = (short)f2bf(a.x); r[1] = (short)f2bf(a.y);
    r[2] = (short)f2bf(a.z); r[3] = (short)f2bf(a.w);
    r[4] = (short)f2bf(b.x); r[5] = (short)f2bf(b.y);
    r[6] = (short)f2bf(b.z); r[7] = (short)f2bf(b.w);
    return r;
}

// ---------------------------------------------------------------------------
// Batched GEMM. Tile 64(M) x 128(N) x 32(K). Block 256 = 4 waves, each 64x32.
// mode 0: NT, W f32 (N,K), out bf16            (kv projections)
// mode 1: NT, W f32 (N,K), out f32 split-K     (qhead / inproj / outproj)
// mode 2: NN, W f32 (K,N) k-major, out f32     (lifts; nkz must be 1)
// Register-prefetch pipelined K-loop. LDS padded: bf16 stride 40 (2-way free),
// f32 stride 132 (conflict-free stores, 4-way frag reads).
// ---------------------------------------------------------------------------
struct SubGemm {
    const float* A; const float* W; const float* bias;
    float* Cf; unsigned short* Ch;
    int K, N, Kc, nj, ni, nkz, mode, ldc;
};
struct GemmBatch { SubGemm d[16]; int start[16]; int nd; };

__global__ __launch_bounds__(256) void gemm_batch(GemmBatch gb)
{
    __shared__ short As[64 * 40];
    __shared__ __align__(16) char Braw[32 * 132 * 4];
    short* Bs  = (short*)Braw;
    float* Bsf = (float*)Braw;

    const int bx = blockIdx.x;
    int di = 0;
#pragma unroll 1
    for (int i = 1; i < gb.nd; ++i) if (bx >= gb.start[i]) di = i;
    const SubGemm g = gb.d[di];
    int local = bx - gb.start[di];
    const int jb = local % g.nj; local /= g.nj;
    const int ib = local % g.ni;
    const int kz = local / g.ni;

    const int tid = threadIdx.x;
    const int w = tid >> 6, lane = tid & 63;
    const int quad = lane >> 4, l16 = lane & 15;
    const int noff = w * 32;

    const int rA = tid >> 2, cA = (tid & 3) * 8;
    const float* pa = g.A + (size_t)(ib * 64 + rA) * g.K + kz * g.Kc + cA;

    floatx4 acc[4][2] = {};

    if (g.mode <= 1) {
        const int rB = tid >> 1, cB = (tid & 1) * 16;
        const float* pb = g.W + (size_t)(jb * 128 + rB) * g.K + kz * g.Kc + cB;
        float4 a0 = *(const float4*)(pa), a1 = *(const float4*)(pa + 4);
        float4 b0 = *(const float4*)(pb),     b1 = *(const float4*)(pb + 4);
        float4 b2 = *(const float4*)(pb + 8), b3 = *(const float4*)(pb + 12);
#pragma unroll 1
        for (int k0 = 0; k0 < g.Kc; k0 += 32) {
            *(short8*)&As[rA * 40 + cA]     = pack8(a0, a1);
            *(short8*)&Bs[rB * 40 + cB]     = pack8(b0, b1);
            *(short8*)&Bs[rB * 40 + cB + 8] = pack8(b2, b3);
            __syncthreads();
            if (k0 + 32 < g.Kc) {
                pa += 32; pb += 32;
                a0 = *(const float4*)(pa);     a1 = *(const float4*)(pa + 4);
                b0 = *(const float4*)(pb);     b1 = *(const float4*)(pb + 4);
                b2 = *(const float4*)(pb + 8); b3 = *(const float4*)(pb + 12);
            }
            short8 af[4], bfr[2];
#pragma unroll
            for (int r = 0; r < 4; ++r)
                af[r] = *(const short8*)&As[(r * 16 + l16) * 40 + quad * 8];
#pragma unroll
            for (int c = 0; c < 2; ++c)
                bfr[c] = *(const short8*)&Bs[(noff + c * 16 + l16) * 40 + quad * 8];
#pragma unroll
            for (int r = 0; r < 4; ++r)
#pragma unroll
                for (int c = 0; c < 2; ++c)
                    acc[r][c] = __builtin_amdgcn_mfma_f32_16x16x32_bf16(af[r], bfr[c], acc[r][c], 0, 0, 0);
            __syncthreads();
        }
    } else {
        const int rK = tid >> 3, cN = (tid & 7) * 16;
        const float* pb = g.W + (size_t)rK * g.N + jb * 128 + cN;
        float4 a0 = *(const float4*)(pa), a1 = *(const float4*)(pa + 4);
        float4 b0 = *(const float4*)(pb),     b1 = *(const float4*)(pb + 4);
        float4 b2 = *(const float4*)(pb + 8), b3 = *(const float4*)(pb + 12);
#pragma unroll 1
        for (int k0 = 0; k0 < g.Kc; k0 += 32) {
            *(short8*)&As[rA * 40 + cA] = pack8(a0, a1);
            *(float4*)&Bsf[rK * 132 + cN]      = b0;
            *(float4*)&Bsf[rK * 132 + cN + 4]  = b1;
            *(float4*)&Bsf[rK * 132 + cN + 8]  = b2;
            *(float4*)&Bsf[rK * 132 + cN + 12] = b3;
            __syncthreads();
            if (k0 + 32 < g.Kc) {
                pa += 32; pb += (size_t)32 * g.N;
                a0 = *(const float4*)(pa);     a1 = *(const float4*)(pa + 4);
                b0 = *(const float4*)(pb);     b1 = *(const float4*)(pb + 4);
                b2 = *(const float4*)(pb + 8); b3 = *(const float4*)(pb + 12);
            }
            short8 af[4], bfr[2];
#pragma unroll
            for (int r = 0; r < 4; ++r)
                af[r] = *(const short8*)&As[(r * 16 + l16) * 40 + quad * 8];
#pragma unroll
            for (int c = 0; c < 2; ++c) {
                const int colb = noff + c * 16 + l16;
#pragma unroll
                for (int i = 0; i < 8; ++i)
                    bfr[c][i] = (short)f2bf(Bsf[(quad * 8 + i) * 132 + colb]);
            }
#pragma unroll
            for (int r = 0; r < 4; ++r)
#pragma unroll
                for (int c = 0; c < 2; ++c)
                    acc[r][c] = __builtin_amdgcn_mfma_f32_16x16x32_bf16(af[r], bfr[c], acc[r][c], 0, 0, 0);
            __syncthreads();
        }
    }

#pragma unroll
    for (int r = 0; r < 4; ++r)
#pragma unroll
        for (int c = 0; c < 2; ++c) {
            const int col = jb * 128 + noff + c * 16 + l16;
            const float bj = (g.mode == 1 && kz != 0) ? 0.f : g.bias[col];
#pragma unroll
            for (int q = 0; q < 4; ++q) {
                const int row = ib * 64 + r * 16 + quad * 4 + q;
                const float v = acc[r][c][q] + bj;
                if (g.mode == 0)
                    g.Ch[(size_t)row * g.ldc + col] = f2bf(v);
                else if (g.mode == 1) {
                    if (g.nkz > 1) atomicAdd(&g.Cf[(size_t)row * g.ldc + col], v);
                    else           g.Cf[(size_t)row * g.ldc + col] = v;
                } else
                    g.Cf[(size_t)row * g.ldc + col] = v;
            }
        }
}

// ---------------------------------------------------------------------------
// qk_batch: S(64b x 128m tile) = 0.125 * Q_h @ K_h^T, all 28 heads batched.
// Grid (16 m-tiles, 28 heads). Block 256.
// ---------------------------------------------------------------------------
__global__ __launch_bounds__(256) void qk_batch(
    const float* __restrict__ qp_t, const float* __restrict__ qp_p, const float* __restrict__ qp_c,
    const unsigned short* __restrict__ kv_t, const unsigned short* __restrict__ kv_p, const unsigned short* __restrict__ kv_c,
    float* __restrict__ S_t, float* __restrict__ S_p, float* __restrict__ S_c)
{
    __shared__ short As[64 * 72];
    __shared__ short Bs[128 * 72];
    const int hy = blockIdx.y;
    const float* qp; const unsigned short* kv; float* S; int d, h;
    if (hy < 4)       { qp = qp_t; kv = kv_t; S = S_t; d = 256;  h = hy; }
    else if (hy < 12) { qp = qp_p; kv = kv_p; S = S_p; d = 512;  h = hy - 4; }
    else              { qp = qp_c; kv = kv_c; S = S_c; d = 1024; h = hy - 12; }

    const int j0 = blockIdx.x * 128;
    const int tid = threadIdx.x;
    const int w = tid >> 6, lane = tid & 63;
    const int quad = lane >> 4, l16 = lane & 15;
    const int noff = w * 32;
    const int twoD = 2 * d;

    {
        const int b = tid >> 2, kc = (tid & 3) * 16;
        const float* ga = qp + (size_t)b * d + h * 64 + kc;
        float4 a0 = *(const float4*)(ga + 0), a1 = *(const float4*)(ga + 4);
        float4 a2 = *(const float4*)(ga + 8), a3 = *(const float4*)(ga + 12);
        *(short8*)&As[b * 72 + kc + 0] = pack8(a0, a1);
        *(short8*)&As[b * 72 + kc + 8] = pack8(a2, a3);
    }
    {
        const int m = tid >> 1, hf = (tid & 1) * 32;
        const unsigned short* gb = kv + (size_t)(j0 + m) * twoD + h * 64 + hf;
        uint4 b0 = *(const uint4*)(gb + 0),  b1 = *(const uint4*)(gb + 8);
        uint4 b2 = *(const uint4*)(gb + 16), b3 = *(const uint4*)(gb + 24);
        *(uint4*)&Bs[m * 72 + hf + 0]  = b0;
        *(uint4*)&Bs[m * 72 + hf + 8]  = b1;
        *(uint4*)&Bs[m * 72 + hf + 16] = b2;
        *(uint4*)&Bs[m * 72 + hf + 24] = b3;
    }
    __syncthreads();

    floatx4 acc[4][2] = {};
#pragma unroll
    for (int k0 = 0; k0 < 64; k0 += 32) {
        short8 af[4], bfr[2];
#pragma unroll
        for (int r = 0; r < 4; ++r)
            af[r] = *(const short8*)&As[(r * 16 + l16) * 72 + k0 + quad * 8];
#pragma unroll
        for (int c = 0; c < 2; ++c)
            bfr[c] = *(const short8*)&Bs[(noff + c * 16 + l16) * 72 + k0 + quad * 8];
#pragma unroll
        for (int r = 0; r < 4; ++r)
#pragma unroll
            for (int c = 0; c < 2; ++c)
                acc[r][c] = __builtin_amdgcn_mfma_f32_16x16x32_bf16(af[r], bfr[c], acc[r][c], 0, 0, 0);
    }
#pragma unroll
    for (int r = 0; r < 4; ++r)
#pragma unroll
        for (int c = 0; c < 2; ++c) {
            int col = j0 + noff + c * 16 + l16;
#pragma unroll
            for (int q = 0; q < 4; ++q) {
                int row = r * 16 + quad * 4 + q;
                S[((size_t)h * 64 + row) * 2048 + col] = acc[r][c][q] * 0.125f;
            }
        }
}

// ---------------------------------------------------------------------------
// softmax_pv_batch: per (head, b): softmax over S row, then P @ V_h.
// Grid (28, 64). Block 256.
// ---------------------------------------------------------------------------
__global__ __launch_bounds__(256) void softmax_pv_batch(
    const float* __restrict__ S_t, const float* __restrict__ S_p, const float* __restrict__ S_c,
    const unsigned short* __restrict__ kv_t, const unsigned short* __restrict__ kv_p, const unsigned short* __restrict__ kv_c,
    const uint8_t* __restrict__ mask,
    float* __restrict__ o_t, float* __restrict__ o_p, float* __restrict__ o_c)
{
    const int hy = blockIdx.x, b = blockIdx.y;
    const float* S; const unsigned short* kv; float* o; int d, h;
    if (hy < 4)       { S = S_t; kv = kv_t; o = o_t; d = 256;  h = hy; }
    else if (hy < 12) { S = S_p; kv = kv_p; o = o_p; d = 512;  h = hy - 4; }
    else              { S = S_c; kv = kv_c; o = o_c; d = 1024; h = hy - 12; }

    const int tid = threadIdx.x;
    __shared__ __align__(16) float sc[2048];
    __shared__ float red[4];
    __shared__ float part[4][64];
    __shared__ float s_max, s_sum;

    const float* Sr = S + ((size_t)h * 64 + b) * 2048;
    const uint8_t* mr = mask + (size_t)b * 2048;

    float lmax = -1e30f;
    for (int m = tid; m < 2048; m += 256) {
        float s = Sr[m];
        if (mr[m]) s = -1e9f;
        sc[m] = s;
        lmax = fmaxf(lmax, s);
    }
#pragma unroll
    for (int off = 32; off; off >>= 1) lmax = fmaxf(lmax, __shfl_down(lmax, off));
    if ((tid & 63) == 0) red[tid >> 6] = lmax;
    __syncthreads();
    if (tid == 0) s_max = fmaxf(fmaxf(red[0], red[1]), fmaxf(red[2], red[3]));
    __syncthreads();
    const float mx = s_max;

    float lsum = 0.f;
    for (int m = tid; m < 2048; m += 256) {
        float e = __expf(sc[m] - mx);
        sc[m] = e;
        lsum += e;
    }
#pragma unroll
    for (int off = 32; off; off >>= 1) lsum += __shfl_down(lsum, off);
    if ((tid & 63) == 0) red[tid >> 6] = lsum;
    __syncthreads();
    if (tid == 0) s_sum = red[0] + red[1] + red[2] + red[3];
    __syncthreads();

    const int lane = tid & 63, w = tid >> 6;
    const int twoD = 2 * d;
    const unsigned short* vcol = kv + d + h * 64 + lane;
    float acc = 0.f;
    const int m0 = w * 512;
#pragma unroll 1
    for (int m = m0; m < m0 + 512; m += 8) {
#pragma unroll
        for (int j = 0; j < 8; ++j)
            acc += sc[m + j] * bflo((unsigned int)vcol[(size_t)(m + j) * twoD]);
    }
    part[w][lane] = acc;
    __syncthreads();
    if (tid < 64) {
        float r = (part[0][tid] + part[1][tid] + part[2][tid] + part[3][tid]) / s_sum;
        o[(size_t)b * d + h * 64 + tid] = r;
    }
}

// ---------------------------------------------------------------------------
__global__ __launch_bounds__(256) void ln_kernel(
    float* __restrict__ x, const float* __restrict__ g, const float* __restrict__ bb)
{
    const int row = blockIdx.x;
    float* xr = x + (size_t)row * 4096;
    const int tid = threadIdx.x;
    float v[16];
    float sum = 0.f, sumsq = 0.f;
#pragma unroll
    for (int i = 0; i < 16; ++i) {
        v[i] = xr[tid + i * 256];
        sum += v[i];
        sumsq += v[i] * v[i];
    }
    __shared__ float rs[4], rq[4];
#pragma unroll
    for (int off = 32; off; off >>= 1) {
        sum += __shfl_down(sum, off);
        sumsq += __shfl_down(sumsq, off);
    }
    if ((tid & 63) == 0) { rs[tid >> 6] = sum; rq[tid >> 6] = sumsq; }
    __syncthreads();
    const float ts = rs[0] + rs[1] + rs[2] + rs[3];
    const float tq = rq[0] + rq[1] + rq[2] + rq[3];
    const float mu = ts * (1.f / 4096.f);
    const float var = tq * (1.f / 4096.f) - mu * mu;
    const float r = rsqrtf(var + 1e-5f);
#pragma unroll
    for (int i = 0; i < 16; ++i) {
        int e = tid + i * 256;
        xr[e] = (v[i] - mu) * r * g[e] + bb[e];
    }
}

// ---------------------------------------------------------------------------
static void addg(GemmBatch& G, int& tot,
                 const float* A, const float* W, const float* bias,
                 float* Cf, unsigned short* Ch,
                 int K, int N, int Kc, int nj, int ni, int nkz, int mode, int ldc)
{
    SubGemm& s = G.d[G.nd];
    s.A = A; s.W = W; s.bias = bias; s.Cf = Cf; s.Ch = Ch;
    s.K = K; s.N = N; s.Kc = Kc; s.nj = nj; s.ni = ni; s.nkz = nkz;
    s.mode = mode; s.ldc = ldc;
    G.start[G.nd] = tot;
    tot += nj * ni * nkz;
    G.nd++;
}

extern "C" void kernel_launch(void* const* d_in, const int* in_sizes, int n_in,
                              void* d_out, int out_size, void* d_ws, size_t ws_size,
                              hipStream_t stream)
{
    const float*   hs     = (const float*)d_in[0];
    const float*   fib_t  = (const float*)d_in[1];
    const float*   fib_p  = (const float*)d_in[2];
    const float*   fib_c  = (const float*)d_in[3];
    const uint8_t* mask   = (const uint8_t*)d_in[4];
    const float* Wq_t   = (const float*)d_in[5];  const float* bq_t   = (const float*)d_in[6];
    const float* Wq_p   = (const float*)d_in[7];  const float* bq_p   = (const float*)d_in[8];
    const float* Wq_c   = (const float*)d_in[9];  const float* bq_c   = (const float*)d_in[10];
    const float* Wqkv_t = (const float*)d_in[11]; const float* bqkv_t = (const float*)d_in[12];
    const float* Wo_t   = (const float*)d_in[13]; const float* bo_t   = (const float*)d_in[14];
    const float* Wqkv_p = (const float*)d_in[15]; const float* bqkv_p = (const float*)d_in[16];
    const float* Wo_p   = (const float*)d_in[17]; const float* bo_p   = (const float*)d_in[18];
    const float* Wqkv_c = (const float*)d_in[19]; const float* bqkv_c = (const float*)d_in[20];
    const float* Wo_c   = (const float*)d_in[21]; const float* bo_c   = (const float*)d_in[22];
    const float* Wl_t   = (const float*)d_in[23]; const float* bl_t   = (const float*)d_in[24];
    const float* Wl_p   = (const float*)d_in[25]; const float* bl_p   = (const float*)d_in[26];
    const float* Wl_c   = (const float*)d_in[27]; const float* bl_c   = (const float*)d_in[28];
    const float* ln_g   = (const float*)d_in[29]; const float* ln_b   = (const float*)d_in[30];

    char* wsb = (char*)d_ws;
    float* q_t  = (float*)wsb; wsb += 64 * 256 * 4;
    float* q_p  = (float*)wsb; wsb += 64 * 512 * 4;
    float* q_c  = (float*)wsb; wsb += 64 * 1024 * 4;
    float* qp_t = (float*)wsb; wsb += 64 * 256 * 4;
    float* qp_p = (float*)wsb; wsb += 64 * 512 * 4;
    float* qp_c = (float*)wsb; wsb += 64 * 1024 * 4;
    float* po_t = (float*)wsb; wsb += 64 * 256 * 4;
    float* po_p = (float*)wsb; wsb += 64 * 512 * 4;
    float* po_c = (float*)wsb; wsb += 64 * 1024 * 4;
    size_t zbytes = (size_t)(wsb - (char*)d_ws);
    float* o_t  = (float*)wsb; wsb += 64 * 256 * 4;
    float* o_p  = (float*)wsb; wsb += 64 * 512 * 4;
    float* o_c  = (float*)wsb; wsb += 64 * 1024 * 4;
    unsigned short* kv_t = (unsigned short*)wsb; wsb += 2048 * 512 * 2;
    unsigned short* kv_p = (unsigned short*)wsb; wsb += 2048 * 1024 * 2;
    unsigned short* kv_c = (unsigned short*)wsb; wsb += 2048 * 2048 * 2;
    float* S_t = (float*)wsb; wsb += (size_t)4  * 64 * 2048 * 4;
    float* S_p = (float*)wsb; wsb += (size_t)8  * 64 * 2048 * 4;
    float* S_c = (float*)wsb; wsb += (size_t)16 * 64 * 2048 * 4;
    float* out = (float*)d_out;

    const dim3 blk(256);
    hipMemsetAsync(d_ws, 0, zbytes, stream);

    // ---- launch 1: kv projections (bf16 out) + bundle query heads (split-K)
    {
        GemmBatch G{}; int tot = 0; G.nd = 0;
        addg(G, tot, fib_c, Wqkv_c + 1024 * 1024, bqkv_c + 1024, nullptr, kv_c, 1024, 2048, 1024, 16, 32, 1, 0, 2048);
        addg(G, tot, fib_p, Wqkv_p + 512 * 512,   bqkv_p + 512,  nullptr, kv_p, 512,  1024, 512,  8,  32, 1, 0, 1024);
        addg(G, tot, fib_t, Wqkv_t + 256 * 256,   bqkv_t + 256,  nullptr, kv_t, 256,  512,  256,  4,  32, 1, 0, 512);
        addg(G, tot, hs, Wq_c, bq_c, q_c, nullptr, 4096, 1024, 256, 8, 1, 16, 1, 1024);
        addg(G, tot, hs, Wq_p, bq_p, q_p, nullptr, 4096, 512,  256, 4, 1, 16, 1, 512);
        addg(G, tot, hs, Wq_t, bq_t, q_t, nullptr, 4096, 256,  256, 2, 1, 16, 1, 256);
        gemm_batch<<<dim3(tot), blk, 0, stream>>>(G);
    }

    // ---- launch 2: q in-proj
    {
        GemmBatch G{}; int tot = 0; G.nd = 0;
        addg(G, tot, q_c, Wqkv_c, bqkv_c, qp_c, nullptr, 1024, 1024, 128, 8, 1, 8, 1, 1024);
        addg(G, tot, q_p, Wqkv_p, bqkv_p, qp_p, nullptr, 512,  512,  64,  4, 1, 8, 1, 512);
        addg(G, tot, q_t, Wqkv_t, bqkv_t, qp_t, nullptr, 256,  256,  64,  2, 1, 4, 1, 256);
        gemm_batch<<<dim3(tot), blk, 0, stream>>>(G);
    }

    // ---- launch 3/4: attention
    qk_batch<<<dim3(16, 28), blk, 0, stream>>>(qp_t, qp_p, qp_c, kv_t, kv_p, kv_c, S_t, S_p, S_c);
    softmax_pv_batch<<<dim3(28, 64), blk, 0, stream>>>(S_t, S_p, S_c, kv_t, kv_p, kv_c, mask, o_t, o_p, o_c);

    // ---- launch 5: out-proj
    {
        GemmBatch G{}; int tot = 0; G.nd = 0;
        addg(G, tot, o_c, Wo_c, bo_c, po_c, nullptr, 1024, 1024, 128, 8, 1, 8, 1, 1024);
        addg(G, tot, o_p, Wo_p, bo_p, po_p, nullptr, 512,  512,  64,  4, 1, 8, 1, 512);
        addg(G, tot, o_t, Wo_t, bo_t, po_t, nullptr, 256,  256,  64,  2, 1, 4, 1, 256);
        gemm_batch<<<dim3(tot), blk, 0, stream>>>(G);
    }

    // ---- launch 6: lifts (NN mode, fp32 W staged in LDS) -> d_out
    {
        GemmBatch G{}; int tot = 0; G.nd = 0;
        for (int z = 0; z < 4; ++z)
            addg(G, tot, po_c, Wl_c + (size_t)z * 1024 * 4096, bl_c + z * 4096,
                 out + (size_t)(12 + z) * 4096, nullptr, 1024, 4096, 1024, 32, 1, 1, 2, 16 * 4096);
        for (int z = 0; z < 8; ++z)
            addg(G, tot, po_p, Wl_p + (size_t)z * 512 * 4096, bl_p + z * 4096,
                 out + (size_t)(4 + z) * 4096, nullptr, 512, 4096, 512, 32, 1, 1, 2, 16 * 4096);
        for (int z = 0; z < 4; ++z)
            addg(G, tot, po_t, Wl_t + (size_t)z * 256 * 4096, bl_t + z * 4096,
                 out + (size_t)z * 4096, nullptr, 256, 4096, 256, 32, 1, 1, 2, 16 * 4096);
        gemm_batch<<<dim3(tot), blk, 0, stream>>>(G);
    }

    // ---- launch 7: layernorm in place
    ln_kernel<<<dim3(1024), blk, 0, stream>>>(out, ln_g, ln_b);
}